// Round 4
// baseline (4548.209 us; speedup 1.0000x reference)
//
#include <hip/hip_runtime.h>
#include <hip/hip_bf16.h>
#include <math.h>

// ---------------- problem constants ----------------
#define BATCH   4096
#define CH      64          // latent channels
#define KCB     512         // codebook size

// d_out layout (floats): x_tilde [4096,1,28,28], z_e_x [4096,64,7,7], z_q_x [4096,64,7,7]
#define XT_N    (BATCH*784)
#define ZE_OFF  (XT_N)
#define ZQ_OFF  (XT_N + BATCH*3136)

// workspace layout (bytes)
#define WS_C1   0                       // conv1 raw: 4096*32*196 floats = 102,760,448 B
#define WS_C2   102760448ULL            // conv2 raw: 4096*16*784 floats = 205,520,896 B
#define WS_ST   308281344ULL            // stats: double sum1[32] sq1[32] sum2[16] sq2[16]
#define WS_BN   308282112ULL            // bn params: float s1[32] h1[32] s2[16] h2[16]
#define WS_W2T  308282496ULL            // w2 transposed [16 taps][32 ic][16 oc] = 32 KiB
// w1t lives in the head of the C2 region: written by prep, read by k2, clobbered by k4 (safe: stream order)
#define WS_W1T  WS_C2

// ---------------- K0: zero the stats accumulators ----------------
__global__ void k_zero(double* __restrict__ stats) {
    int t = threadIdx.x;
    if (t < 96) stats[t] = 0.0;
}

// ---------------- prep: transpose weights for scalar-load access ----------------
// w1 [ic64][oc32][kh][kw] -> w1t [(kh*4+kw)*64+ic][oc32]
// w2 [ic32][oc16][kh][kw] -> w2t [(kh*4+kw)*32+ic][oc16]
__global__ void k_prep(const float* __restrict__ w1, const float* __restrict__ w2,
                       float* __restrict__ w1t, float* __restrict__ w2t) {
    int t = threadIdx.x + blockIdx.x * 256;
    if (t < 32768) {
        int ic = t >> 9, oc = (t >> 4) & 31, khw = t & 15;
        w1t[(khw * 64 + ic) * 32 + oc] = w1[t];
    }
    if (t < 8192) {
        int ic = t >> 8, oc = (t >> 4) & 15, khw = t & 15;
        w2t[(khw * 32 + ic) * 16 + oc] = w2[t];
    }
}

// ---------------- K1: gather + VQ argmin + z_e_x/z_q_x ----------------
__global__ __launch_bounds__(256) void k1_encode(
    const int* __restrict__ xidx, const float* __restrict__ encW,
    const float* __restrict__ emb, float* __restrict__ out)
{
    __shared__ float ee_s[KCB];
    const int tid = threadIdx.x;

    for (int k = tid; k < KCB; k += 256) {
        const float* e = emb + (k << 6);
        float s = 0.f;
        #pragma unroll
        for (int c = 0; c < CH; ++c) s = fmaf(e[c], e[c], s);
        ee_s[k] = s;
    }
    __syncthreads();

    const int p  = blockIdx.x*256 + tid;     // < 200704 exactly
    const int b  = p / 49;
    const int hw = p - b*49;
    const long long row = xidx[b];
    const float* rp = encW + row*3136LL + hw;
    float* zep = out + ZE_OFF + (long long)b*3136 + hw;

    float z[CH];
    float zz = 0.f;
    #pragma unroll
    for (int c = 0; c < CH; ++c) {
        float v = rp[c*49];
        z[c] = v;
        zep[c*49] = v;                       // z_e_x is an exact row copy
        zz = fmaf(v, v, zz);
    }

    float d0 = 3.4e38f, d1 = 3.4e38f;
    int k0 = 0, k1i = 1;
    for (int k = 0; k < KCB; k += 2) {
        const float4* ea4 = (const float4*)(emb + (k << 6));      // uniform -> s_load
        const float4* eb4 = (const float4*)(emb + (k << 6) + 64); // uniform -> s_load
        float a0=0.f,a1=0.f,a2=0.f,a3=0.f, c0=0.f,c1=0.f,c2=0.f,c3=0.f;
        #pragma unroll
        for (int j = 0; j < 16; ++j) {
            float4 ea = ea4[j];
            float4 eb = eb4[j];
            a0 = fmaf(z[4*j+0], ea.x, a0);
            a1 = fmaf(z[4*j+1], ea.y, a1);
            a2 = fmaf(z[4*j+2], ea.z, a2);
            a3 = fmaf(z[4*j+3], ea.w, a3);
            c0 = fmaf(z[4*j+0], eb.x, c0);
            c1 = fmaf(z[4*j+1], eb.y, c1);
            c2 = fmaf(z[4*j+2], eb.z, c2);
            c3 = fmaf(z[4*j+3], eb.w, c3);
        }
        float dotA = (a0+a1) + (a2+a3);
        float dotB = (c0+c1) + (c2+c3);
        float dA = (zz - 2.f*dotA) + ee_s[k];
        float dB = (zz - 2.f*dotB) + ee_s[k+1];
        if (dA < d0)      { d1 = d0; k1i = k0; d0 = dA; k0 = k; }
        else if (dA < d1) { d1 = dA; k1i = k; }
        if (dB < d0)      { d1 = d0; k1i = k0; d0 = dB; k0 = k+1; }
        else if (dB < d1) { d1 = dB; k1i = k+1; }
    }

    // fp64 refine of near-ties -> effectively exact argmin
    if (d1 - d0 < fmaxf(1e-6f, 1e-3f * fabsf(d0))) {
        double D0 = 0.0, D1 = 0.0;
        #pragma unroll
        for (int c = 0; c < CH; ++c) {
            double f0 = (double)z[c] - (double)emb[k0*CH + c];
            double f1 = (double)z[c] - (double)emb[k1i*CH + c];
            D0 += f0*f0; D1 += f1*f1;
        }
        if (D1 < D0 || (D1 == D0 && k1i < k0)) k0 = k1i;
    }

    float* zqp = out + ZQ_OFF + (long long)b*3136 + hw;
    const float* e0 = emb + k0*CH;
    #pragma unroll
    for (int c = 0; c < CH; ++c) zqp[c*49] = e0[c];
}

#define OC8(A, xc, wr) { \
    (A)[0]=fmaf((xc),(wr)[0],(A)[0]); (A)[1]=fmaf((xc),(wr)[1],(A)[1]); \
    (A)[2]=fmaf((xc),(wr)[2],(A)[2]); (A)[3]=fmaf((xc),(wr)[3],(A)[3]); \
    (A)[4]=fmaf((xc),(wr)[4],(A)[4]); (A)[5]=fmaf((xc),(wr)[5],(A)[5]); \
    (A)[6]=fmaf((xc),(wr)[6],(A)[6]); (A)[7]=fmaf((xc),(wr)[7],(A)[7]); }

// ---------------- K2: deconv1 (64->32, 7->14) + bias, BN1 stats ----------------
// 1 image per block; wave -> 8 oc; lanes -> 49 base pixels; pw-paired float2 stores
__global__ __launch_bounds__(256) void k2_deconv1(
    const float* __restrict__ zq, const float* __restrict__ w1t,
    const float* __restrict__ b1, float* __restrict__ c1raw,
    double* __restrict__ stats)
{
    __shared__ float x_s[81*64];        // XOR-swizzled [9x9 rows][64ch], 20.25 KiB
    __shared__ float bs[32], bq[32];

    const int tid  = threadIdx.x;
    const int wave = tid >> 6;
    const int lane = tid & 63;
    const int b    = blockIdx.x;

    for (int i = tid; i < 81*64; i += 256) x_s[i] = 0.f;
    if (tid < 32) { bs[tid] = 0.f; bq[tid] = 0.f; }
    __syncthreads();

    const float* zb = zq + (long long)b*3136;
    for (int i = tid; i < 3136; i += 256) {
        int c = i / 49, hw = i - c*49;
        int ih = hw / 7, iw = hw - ih*7;
        int r = (ih+1)*9 + (iw+1);
        int slot = (c >> 2) ^ (r & 7);
        x_s[r*64 + (slot << 2) + (c & 3)] = zb[i];
    }
    __syncthreads();

    const int oc0u = __builtin_amdgcn_readfirstlane(wave << 3);
    float bias[8];
    #pragma unroll
    for (int j = 0; j < 8; ++j) bias[j] = b1[oc0u + j];

    const bool act = lane < 49;
    const int  la  = act ? lane : 0;
    const int  a   = la / 7;
    const int  bb  = la - a*7;

    float ts[8], tq[8];
    #pragma unroll
    for (int j = 0; j < 8; ++j) { ts[j] = 0.f; tq[j] = 0.f; }

    float* c1b = c1raw + (long long)b*6272;

    #pragma unroll
    for (int ph = 0; ph < 2; ++ph) {
        float acc[2][8];
        #pragma unroll
        for (int pw = 0; pw < 2; ++pw) {
            #pragma unroll
            for (int j = 0; j < 8; ++j) acc[pw][j] = 0.f;
            #pragma unroll
            for (int dh = 0; dh < 2; ++dh) {
                #pragma unroll
                for (int dw = 0; dw < 2; ++dw) {
                    const int ih = a + ph - dh, iw = bb + pw - dw;
                    const int r  = (ih+1)*9 + (iw+1);
                    const int rx = r & 7;
                    const int rbase = r*64;
                    const int kh = (1-ph) + 2*dh, kw = (1-pw) + 2*dw;
                    const float* wb = w1t + (((kh<<2)+kw) << 11) + oc0u;   // uniform
                    #pragma unroll
                    for (int ic4 = 0; ic4 < 16; ++ic4) {
                        const float4 xv = *(const float4*)&x_s[rbase + ((ic4 ^ rx) << 2)];
                        const float* wr = wb + (ic4 << 7);                  // uniform
                        OC8(acc[pw], xv.x, wr); OC8(acc[pw], xv.y, wr+32);
                        OC8(acc[pw], xv.z, wr+64); OC8(acc[pw], xv.w, wr+96);
                    }
                }
            }
        }
        if (act) {
            const int off = (2*a + ph)*14 + 2*bb;
            #pragma unroll
            for (int j = 0; j < 8; ++j) {
                float v0 = acc[0][j] + bias[j];
                float v1 = acc[1][j] + bias[j];
                *(float2*)&c1b[(oc0u + j)*196 + off] = make_float2(v0, v1);
                ts[j] += v0 + v1;
                tq[j] = fmaf(v0, v0, tq[j]); tq[j] = fmaf(v1, v1, tq[j]);
            }
        }
    }

    #pragma unroll
    for (int j = 0; j < 8; ++j) {
        atomicAdd(&bs[oc0u + j], ts[j]);
        atomicAdd(&bq[oc0u + j], tq[j]);
    }
    __syncthreads();
    if (tid < 32) {
        atomicAdd(&stats[tid],      (double)bs[tid]);
        atomicAdd(&stats[32 + tid], (double)bq[tid]);
    }
}

// ---------------- K3/K5: fold BN stats into scale/shift ----------------
__global__ void k_bnfin(const double* __restrict__ stats, const float* __restrict__ g,
                        const float* __restrict__ be, float* __restrict__ bn,
                        int soff, int boff, int nch, double n)
{
    int t = threadIdx.x;
    if (t < nch) {
        double mean = stats[soff + t] / n;
        double var  = stats[soff + nch + t] / n - mean*mean;
        double rstd = 1.0 / sqrt(var + 1e-5);
        double sc   = (double)g[t] * rstd;
        bn[boff + t]       = (float)sc;
        bn[boff + nch + t] = (float)((double)be[t] - mean*sc);
    }
}

// ---------------- K4: BN1+ReLU on read, deconv2 (32->16, 14->28), BN2 stats ----------------
// 1 image per block, 256 threads / 4 waves; wave -> (oc half, px half); pw-paired float2 stores
__global__ __launch_bounds__(256) void k4_deconv2(
    const float* __restrict__ c1raw, const float* __restrict__ w2t,
    const float* __restrict__ b2, const float* __restrict__ bn,
    float* __restrict__ c2raw, double* __restrict__ stats)
{
    __shared__ float x_s[256*32];       // XOR-swizzled [16x16 rows][32ch], 32 KiB
    __shared__ float bs[16], bq[16];

    const int tid  = threadIdx.x;
    const int wave = tid >> 6;
    const int lane = tid & 63;
    const int b    = blockIdx.x;

    for (int i = tid; i < 256*32; i += 256) x_s[i] = 0.f;
    if (tid < 16) { bs[tid] = 0.f; bq[tid] = 0.f; }
    __syncthreads();

    const float* cb = c1raw + (long long)b*6272;
    for (int i = tid; i < 6272; i += 256) {
        int ic = i / 196, hw = i - ic*196;
        int ih = hw / 14, iw = hw - ih*14;
        float v = fmaxf(fmaf(cb[i], bn[ic], bn[32 + ic]), 0.f);
        int r = (ih+1)*16 + (iw+1);
        int slot = (ic >> 2) ^ (r & 7);
        x_s[r*32 + (slot << 2) + (ic & 3)] = v;
    }
    __syncthreads();

    const int oc0u   = __builtin_amdgcn_readfirstlane((wave & 1) << 3);
    const int pxhalf = wave >> 1;       // 0,1 -> pixels [pxhalf*98, pxhalf*98+98)
    float bias[8];
    #pragma unroll
    for (int j = 0; j < 8; ++j) bias[j] = b2[oc0u + j];

    const bool act = lane < 49;

    float ts[8], tq[8];
    #pragma unroll
    for (int j = 0; j < 8; ++j) { ts[j] = 0.f; tq[j] = 0.f; }

    float* c2b = c2raw + (long long)b*12544;

    for (int s = 0; s < 2; ++s) {
        const int q  = pxhalf*98 + s*49 + (act ? lane : 0);   // 0..195
        const int a  = q / 14;
        const int bb = q - a*14;
        #pragma unroll
        for (int ph = 0; ph < 2; ++ph) {
            float acc[2][8];
            #pragma unroll
            for (int pw = 0; pw < 2; ++pw) {
                #pragma unroll
                for (int j = 0; j < 8; ++j) acc[pw][j] = 0.f;
                #pragma unroll
                for (int dh = 0; dh < 2; ++dh) {
                    #pragma unroll
                    for (int dw = 0; dw < 2; ++dw) {
                        const int ih = a + ph - dh, iw = bb + pw - dw;
                        const int r  = (ih+1)*16 + (iw+1);
                        const int rx = r & 7;
                        const int rbase = r*32;
                        const int kh = (1-ph) + 2*dh, kw = (1-pw) + 2*dw;
                        const float* wb = w2t + (((kh<<2)+kw) << 9) + oc0u;  // uniform
                        #pragma unroll
                        for (int ic4 = 0; ic4 < 8; ++ic4) {
                            const float4 xv = *(const float4*)&x_s[rbase + ((ic4 ^ rx) << 2)];
                            const float* wr = wb + (ic4 << 6);               // uniform
                            OC8(acc[pw], xv.x, wr); OC8(acc[pw], xv.y, wr+16);
                            OC8(acc[pw], xv.z, wr+32); OC8(acc[pw], xv.w, wr+48);
                        }
                    }
                }
            }
            if (act) {
                const int off = (2*a + ph)*28 + 2*bb;
                #pragma unroll
                for (int j = 0; j < 8; ++j) {
                    float v0 = acc[0][j] + bias[j];
                    float v1 = acc[1][j] + bias[j];
                    *(float2*)&c2b[(oc0u + j)*784 + off] = make_float2(v0, v1);
                    ts[j] += v0 + v1;
                    tq[j] = fmaf(v0, v0, tq[j]); tq[j] = fmaf(v1, v1, tq[j]);
                }
            }
        }
    }

    #pragma unroll
    for (int j = 0; j < 8; ++j) {
        atomicAdd(&bs[oc0u + j], ts[j]);
        atomicAdd(&bq[oc0u + j], tq[j]);
    }
    __syncthreads();
    if (tid < 16) {
        atomicAdd(&stats[64 + tid], (double)bs[tid]);
        atomicAdd(&stats[80 + tid], (double)bq[tid]);
    }
}

// ---------------- K6: BN2+ReLU on read, 3x3 conv 16->1, sigmoid ----------------
// image split into top/bottom halves: grid 8192, 31-float row stride staggers banks
__global__ __launch_bounds__(256) void k6_conv(
    const float* __restrict__ c2raw, const float* __restrict__ cw,
    const float* __restrict__ cbias, const float* __restrict__ bn,
    float* __restrict__ out)
{
    __shared__ float x_s[16*31*16];     // [16 rows][31 col-slots][16 ch] 31 KiB
    __shared__ float w_s[144];          // [khw=9][ic=16]

    const int tid  = threadIdx.x;
    const int b    = blockIdx.x >> 1;
    const int half = blockIdx.x & 1;
    const int r0   = half*14 - 1;       // first staged input row (may be -1)

    for (int i = tid; i < 16*31*16; i += 256) x_s[i] = 0.f;
    if (tid < 144) {
        int ic = tid / 9, khw = tid - ic*9;   // cw is [ic=16][kh][kw]
        w_s[khw*16 + ic] = cw[tid];
    }
    __syncthreads();

    const float* cr = c2raw + (long long)b*12544;
    for (int i = tid; i < 7168; i += 256) {
        int c = i / 448, rem = i - c*448;
        int rr = rem / 28, iw = rem - rr*28;
        int ih = r0 + rr;
        if ((unsigned)ih < 28u) {
            float v = fmaxf(fmaf(cr[c*784 + ih*28 + iw], bn[64 + c], bn[80 + c]), 0.f);
            x_s[(rr*31 + (iw+1))*16 + c] = v;
        }
    }
    __syncthreads();

    const float bias = cbias[0];
    for (int pass = 0; pass < 2; ++pass) {
        int px = tid + (pass << 8);
        if (px >= 392) break;
        int ohl = px / 28, ow = px - ohl*28;
        float a0=0.f,a1=0.f,a2=0.f,a3=0.f;
        #pragma unroll
        for (int kh = 0; kh < 3; ++kh) {
            #pragma unroll
            for (int kw = 0; kw < 3; ++kw) {
                const float4* xv = (const float4*)&x_s[((ohl+kh)*31 + ow+kw)*16];
                const float4* wv = (const float4*)&w_s[((kh*3 + kw) << 4)];
                #pragma unroll
                for (int c4 = 0; c4 < 4; ++c4) {
                    float4 xx = xv[c4];
                    float4 ww = wv[c4];
                    a0 = fmaf(xx.x, ww.x, a0);
                    a1 = fmaf(xx.y, ww.y, a1);
                    a2 = fmaf(xx.z, ww.z, a2);
                    a3 = fmaf(xx.w, ww.w, a3);
                }
            }
        }
        float t = ((a0+a1) + (a2+a3)) + bias;
        out[(long long)b*784 + (half*14 + ohl)*28 + ow] = 1.f / (1.f + expf(-t));
    }
}

// ---------------- launch ----------------
extern "C" void kernel_launch(void* const* d_in, const int* in_sizes, int n_in,
                              void* d_out, int out_size, void* d_ws, size_t ws_size,
                              hipStream_t stream) {
    const int*   x    = (const int*)d_in[0];
    const float* encW = (const float*)d_in[1];
    const float* emb  = (const float*)d_in[2];
    const float* w1   = (const float*)d_in[3];
    const float* b1   = (const float*)d_in[4];
    const float* g1   = (const float*)d_in[5];
    const float* be1  = (const float*)d_in[6];
    const float* w2   = (const float*)d_in[7];
    const float* b2   = (const float*)d_in[8];
    const float* g2   = (const float*)d_in[9];
    const float* be2  = (const float*)d_in[10];
    const float* cw   = (const float*)d_in[11];
    const float* cb   = (const float*)d_in[12];
    float* out = (float*)d_out;

    char* ws = (char*)d_ws;
    float*  c1raw = (float*)(ws + WS_C1);
    float*  c2raw = (float*)(ws + WS_C2);
    double* stats = (double*)(ws + WS_ST);
    float*  bn    = (float*)(ws + WS_BN);
    float*  w1t   = (float*)(ws + WS_W1T);
    float*  w2t   = (float*)(ws + WS_W2T);

    k_zero<<<1, 128, 0, stream>>>(stats);
    k_prep<<<128, 256, 0, stream>>>(w1, w2, w1t, w2t);
    k1_encode<<<784, 256, 0, stream>>>(x, encW, emb, out);
    k2_deconv1<<<4096, 256, 0, stream>>>(out + ZQ_OFF, w1t, b1, c1raw, stats);
    k_bnfin<<<1, 64, 0, stream>>>(stats, g1, be1, bn, 0, 0, 32, 4096.0*196.0);
    k4_deconv2<<<4096, 256, 0, stream>>>(c1raw, w2t, b2, bn, c2raw, stats);
    k_bnfin<<<1, 64, 0, stream>>>(stats, g2, be2, bn, 64, 64, 16, 4096.0*784.0);
    k6_conv<<<8192, 256, 0, stream>>>(c2raw, cw, cb, bn, out);
}

// Round 5
// 1868.491 us; speedup vs baseline: 2.4342x; 2.4342x over previous
//
#include <hip/hip_runtime.h>
#include <hip/hip_bf16.h>
#include <math.h>

// ---------------- problem constants ----------------
#define BATCH   4096
#define CH      64          // latent channels
#define KCB     512         // codebook size

// d_out layout (floats): x_tilde [4096,1,28,28], z_e_x [4096,64,7,7], z_q_x [4096,64,7,7]
#define XT_N    (BATCH*784)
#define ZE_OFF  (XT_N)
#define ZQ_OFF  (XT_N + BATCH*3136)

// workspace layout (bytes)
#define WS_C1   0                       // conv1 raw: 4096*32*196 floats = 102,760,448 B
#define WS_C2   102760448ULL            // conv2 raw: 4096*16*784 floats = 205,520,896 B
#define WS_ST   308281344ULL            // stats: double sum1[32] sq1[32] sum2[16] sq2[16]
#define WS_BN   308282112ULL            // bn params: float s1[32] h1[32] s2[16] h2[16]
#define WS_W2T  308282496ULL            // w2 transposed [16 taps][32 ic][16 oc] = 32 KiB
// w1t lives in the head of the C2 region: written by prep, read by k2, clobbered by k4 (safe: stream order)
#define WS_W1T  WS_C2

// ---------------- K0: zero the stats accumulators ----------------
__global__ void k_zero(double* __restrict__ stats) {
    int t = threadIdx.x;
    if (t < 96) stats[t] = 0.0;
}

// ---------------- prep: transpose weights for scalar-load access ----------------
// w1 [ic64][oc32][kh][kw] -> w1t [(kh*4+kw)*64+ic][oc32]
// w2 [ic32][oc16][kh][kw] -> w2t [(kh*4+kw)*32+ic][oc16]
__global__ void k_prep(const float* __restrict__ w1, const float* __restrict__ w2,
                       float* __restrict__ w1t, float* __restrict__ w2t) {
    int t = threadIdx.x + blockIdx.x * 256;
    if (t < 32768) {
        int ic = t >> 9, oc = (t >> 4) & 31, khw = t & 15;
        w1t[(khw * 64 + ic) * 32 + oc] = w1[t];
    }
    if (t < 8192) {
        int ic = t >> 8, oc = (t >> 4) & 15, khw = t & 15;
        w2t[(khw * 32 + ic) * 16 + oc] = w2[t];
    }
}

// ---------------- K1: gather + VQ argmin + z_e_x/z_q_x ----------------
__global__ __launch_bounds__(256) void k1_encode(
    const int* __restrict__ xidx, const float* __restrict__ encW,
    const float* __restrict__ emb, float* __restrict__ out)
{
    __shared__ float ee_s[KCB];
    const int tid = threadIdx.x;

    for (int k = tid; k < KCB; k += 256) {
        const float* e = emb + (k << 6);
        float s = 0.f;
        #pragma unroll
        for (int c = 0; c < CH; ++c) s = fmaf(e[c], e[c], s);
        ee_s[k] = s;
    }
    __syncthreads();

    const int p  = blockIdx.x*256 + tid;     // < 200704 exactly
    const int b  = p / 49;
    const int hw = p - b*49;
    const long long row = xidx[b];
    const float* rp = encW + row*3136LL + hw;
    float* zep = out + ZE_OFF + (long long)b*3136 + hw;

    float z[CH];
    float zz = 0.f;
    #pragma unroll
    for (int c = 0; c < CH; ++c) {
        float v = rp[c*49];
        z[c] = v;
        zep[c*49] = v;                       // z_e_x is an exact row copy
        zz = fmaf(v, v, zz);
    }

    float d0 = 3.4e38f, d1 = 3.4e38f;
    int k0 = 0, k1i = 1;
    for (int k = 0; k < KCB; k += 2) {
        const float4* ea4 = (const float4*)(emb + (k << 6));      // uniform -> s_load
        const float4* eb4 = (const float4*)(emb + (k << 6) + 64); // uniform -> s_load
        float a0=0.f,a1=0.f,a2=0.f,a3=0.f, c0=0.f,c1=0.f,c2=0.f,c3=0.f;
        #pragma unroll
        for (int j = 0; j < 16; ++j) {
            float4 ea = ea4[j];
            float4 eb = eb4[j];
            a0 = fmaf(z[4*j+0], ea.x, a0);
            a1 = fmaf(z[4*j+1], ea.y, a1);
            a2 = fmaf(z[4*j+2], ea.z, a2);
            a3 = fmaf(z[4*j+3], ea.w, a3);
            c0 = fmaf(z[4*j+0], eb.x, c0);
            c1 = fmaf(z[4*j+1], eb.y, c1);
            c2 = fmaf(z[4*j+2], eb.z, c2);
            c3 = fmaf(z[4*j+3], eb.w, c3);
        }
        float dotA = (a0+a1) + (a2+a3);
        float dotB = (c0+c1) + (c2+c3);
        float dA = (zz - 2.f*dotA) + ee_s[k];
        float dB = (zz - 2.f*dotB) + ee_s[k+1];
        if (dA < d0)      { d1 = d0; k1i = k0; d0 = dA; k0 = k; }
        else if (dA < d1) { d1 = dA; k1i = k; }
        if (dB < d0)      { d1 = d0; k1i = k0; d0 = dB; k0 = k+1; }
        else if (dB < d1) { d1 = dB; k1i = k+1; }
    }

    // fp64 refine of near-ties -> effectively exact argmin
    if (d1 - d0 < fmaxf(1e-6f, 1e-3f * fabsf(d0))) {
        double D0 = 0.0, D1 = 0.0;
        #pragma unroll
        for (int c = 0; c < CH; ++c) {
            double f0 = (double)z[c] - (double)emb[k0*CH + c];
            double f1 = (double)z[c] - (double)emb[k1i*CH + c];
            D0 += f0*f0; D1 += f1*f1;
        }
        if (D1 < D0 || (D1 == D0 && k1i < k0)) k0 = k1i;
    }

    float* zqp = out + ZQ_OFF + (long long)b*3136 + hw;
    const float* e0 = emb + k0*CH;
    #pragma unroll
    for (int c = 0; c < CH; ++c) zqp[c*49] = e0[c];
}

#define OC8(A, xc, wr) { \
    (A)[0]=fmaf((xc),(wr)[0],(A)[0]); (A)[1]=fmaf((xc),(wr)[1],(A)[1]); \
    (A)[2]=fmaf((xc),(wr)[2],(A)[2]); (A)[3]=fmaf((xc),(wr)[3],(A)[3]); \
    (A)[4]=fmaf((xc),(wr)[4],(A)[4]); (A)[5]=fmaf((xc),(wr)[5],(A)[5]); \
    (A)[6]=fmaf((xc),(wr)[6],(A)[6]); (A)[7]=fmaf((xc),(wr)[7],(A)[7]); }

// ---------------- K2: deconv1 (64->32, 7->14) + bias, BN1 stats ----------------
// 1 image per block; wave -> 8 oc; lanes -> 49 base pixels; pw-paired float2 stores
__global__ __launch_bounds__(256) void k2_deconv1(
    const float* __restrict__ zq, const float* __restrict__ w1t,
    const float* __restrict__ b1, float* __restrict__ c1raw,
    double* __restrict__ stats)
{
    __shared__ float x_s[81*64];        // XOR-swizzled [9x9 rows][64ch], 20.25 KiB
    __shared__ float bs[32], bq[32];

    const int tid  = threadIdx.x;
    const int wave = tid >> 6;
    const int lane = tid & 63;
    const int b    = blockIdx.x;

    for (int i = tid; i < 81*64; i += 256) x_s[i] = 0.f;
    if (tid < 32) { bs[tid] = 0.f; bq[tid] = 0.f; }
    __syncthreads();

    const float* zb = zq + (long long)b*3136;
    for (int i = tid; i < 3136; i += 256) {
        int c = i / 49, hw = i - c*49;
        int ih = hw / 7, iw = hw - ih*7;
        int r = (ih+1)*9 + (iw+1);
        int slot = (c >> 2) ^ (r & 7);
        x_s[r*64 + (slot << 2) + (c & 3)] = zb[i];
    }
    __syncthreads();

    const int oc0u = __builtin_amdgcn_readfirstlane(wave << 3);
    float bias[8];
    #pragma unroll
    for (int j = 0; j < 8; ++j) bias[j] = b1[oc0u + j];

    const bool act = lane < 49;
    const int  la  = act ? lane : 0;
    const int  a   = la / 7;
    const int  bb  = la - a*7;

    float ts[8], tq[8];
    #pragma unroll
    for (int j = 0; j < 8; ++j) { ts[j] = 0.f; tq[j] = 0.f; }

    float* c1b = c1raw + (long long)b*6272;

    #pragma unroll
    for (int ph = 0; ph < 2; ++ph) {
        float acc[2][8];
        #pragma unroll
        for (int pw = 0; pw < 2; ++pw) {
            #pragma unroll
            for (int j = 0; j < 8; ++j) acc[pw][j] = 0.f;
            #pragma unroll
            for (int dh = 0; dh < 2; ++dh) {
                #pragma unroll
                for (int dw = 0; dw < 2; ++dw) {
                    const int ih = a + ph - dh, iw = bb + pw - dw;
                    const int r  = (ih+1)*9 + (iw+1);
                    const int rx = r & 7;
                    const int rbase = r*64;
                    const int kh = (1-ph) + 2*dh, kw = (1-pw) + 2*dw;
                    const float* wb = w1t + (((kh<<2)+kw) << 11) + oc0u;   // uniform
                    #pragma unroll
                    for (int ic4 = 0; ic4 < 16; ++ic4) {
                        const float4 xv = *(const float4*)&x_s[rbase + ((ic4 ^ rx) << 2)];
                        const float* wr = wb + (ic4 << 7);                  // uniform
                        OC8(acc[pw], xv.x, wr); OC8(acc[pw], xv.y, wr+32);
                        OC8(acc[pw], xv.z, wr+64); OC8(acc[pw], xv.w, wr+96);
                    }
                }
            }
        }
        if (act) {
            const int off = (2*a + ph)*14 + 2*bb;
            #pragma unroll
            for (int j = 0; j < 8; ++j) {
                float v0 = acc[0][j] + bias[j];
                float v1 = acc[1][j] + bias[j];
                *(float2*)&c1b[(oc0u + j)*196 + off] = make_float2(v0, v1);
                ts[j] += v0 + v1;
                tq[j] = fmaf(v0, v0, tq[j]); tq[j] = fmaf(v1, v1, tq[j]);
            }
        }
    }

    #pragma unroll
    for (int j = 0; j < 8; ++j) {
        atomicAdd(&bs[oc0u + j], ts[j]);
        atomicAdd(&bq[oc0u + j], tq[j]);
    }
    __syncthreads();
    if (tid < 32) {
        atomicAdd(&stats[tid],      (double)bs[tid]);
        atomicAdd(&stats[32 + tid], (double)bq[tid]);
    }
}

// ---------------- K3/K5: fold BN stats into scale/shift ----------------
__global__ void k_bnfin(const double* __restrict__ stats, const float* __restrict__ g,
                        const float* __restrict__ be, float* __restrict__ bn,
                        int soff, int boff, int nch, double n)
{
    int t = threadIdx.x;
    if (t < nch) {
        double mean = stats[soff + t] / n;
        double var  = stats[soff + nch + t] / n - mean*mean;
        double rstd = 1.0 / sqrt(var + 1e-5);
        double sc   = (double)g[t] * rstd;
        bn[boff + t]       = (float)sc;
        bn[boff + nch + t] = (float)((double)be[t] - mean*sc);
    }
}

// ---------------- K4: BN1+ReLU on read, deconv2 (32->16, 14->28), BN2 stats ----------------
// ROUND-2 STRUCTURE (proven fast): 256 threads; wave -> (oc half, px half);
// cls-sequential, single acc[8], scalar stores. Do NOT pair pw / double the
// accumulators here: that variant (r3/r4) blew VGPR to 172, capped occupancy
// at ~12%, and ran 3391 us vs <=~600 us for this one.
__global__ __launch_bounds__(256) void k4_deconv2(
    const float* __restrict__ c1raw, const float* __restrict__ w2t,
    const float* __restrict__ b2, const float* __restrict__ bn,
    float* __restrict__ c2raw, double* __restrict__ stats)
{
    __shared__ float x_s[256*32];       // XOR-swizzled [16x16 rows][32ch], 32 KiB
    __shared__ float bs[16], bq[16];

    const int tid  = threadIdx.x;
    const int wave = tid >> 6;
    const int lane = tid & 63;
    const int b    = blockIdx.x;

    for (int i = tid; i < 256*32; i += 256) x_s[i] = 0.f;
    if (tid < 16) { bs[tid] = 0.f; bq[tid] = 0.f; }
    __syncthreads();

    const float* cb = c1raw + (long long)b*6272;
    for (int i = tid; i < 6272; i += 256) {
        int ic = i / 196, hw = i - ic*196;
        int ih = hw / 14, iw = hw - ih*14;
        float v = fmaxf(fmaf(cb[i], bn[ic], bn[32 + ic]), 0.f);
        int r = (ih+1)*16 + (iw+1);
        int slot = (ic >> 2) ^ (r & 7);
        x_s[r*32 + (slot << 2) + (ic & 3)] = v;
    }
    __syncthreads();

    const int oc0u   = __builtin_amdgcn_readfirstlane((wave & 1) << 3);
    const int pxhalf = wave >> 1;
    float bias[8];
    #pragma unroll
    for (int j = 0; j < 8; ++j) bias[j] = b2[oc0u + j];

    float ts[8], tq[8];
    #pragma unroll
    for (int j = 0; j < 8; ++j) { ts[j] = 0.f; tq[j] = 0.f; }

    float* c2b = c2raw + (long long)b*12544;

    for (int cls = 0; cls < 4; ++cls) {
        const int ph = cls >> 1, pw = cls & 1;
        for (int s = 0; s < 2; ++s) {
            const int qi  = s*64 + lane;
            const bool act = qi < 98;
            const int  q   = pxhalf*98 + (act ? qi : 0);
            const int  a   = q / 14;
            const int  bb  = q - a*14;
            const int  oh = 2*a + ph, ow = 2*bb + pw;
            float acc[8];
            #pragma unroll
            for (int j = 0; j < 8; ++j) acc[j] = 0.f;
            #pragma unroll
            for (int dh = 0; dh < 2; ++dh) {
                #pragma unroll
                for (int dw = 0; dw < 2; ++dw) {
                    const int ih = a + ph - dh, iw = bb + pw - dw;
                    const int r  = (ih+1)*16 + (iw+1);
                    const int rx = r & 7;
                    const int rbase = r*32;
                    const int kh = (1-ph) + 2*dh, kw = (1-pw) + 2*dw;
                    const float* wb = w2t + (((kh<<2)+kw) << 9) + oc0u;    // uniform
                    #pragma unroll
                    for (int ic4 = 0; ic4 < 8; ++ic4) {
                        const float4 xv = *(const float4*)&x_s[rbase + ((ic4 ^ rx) << 2)];
                        const float* wr = wb + (ic4 << 6);                  // uniform
                        OC8(acc, xv.x, wr); OC8(acc, xv.y, wr+16);
                        OC8(acc, xv.z, wr+32); OC8(acc, xv.w, wr+48);
                    }
                }
            }
            if (act) {
                float* cp = c2b + oh*28 + ow;
                #pragma unroll
                for (int j = 0; j < 8; ++j) {
                    float v = acc[j] + bias[j];
                    cp[(oc0u + j)*784] = v;
                    ts[j] += v; tq[j] = fmaf(v, v, tq[j]);
                }
            }
        }
    }

    #pragma unroll
    for (int j = 0; j < 8; ++j) {
        atomicAdd(&bs[oc0u + j], ts[j]);
        atomicAdd(&bq[oc0u + j], tq[j]);
    }
    __syncthreads();
    if (tid < 16) {
        atomicAdd(&stats[64 + tid], (double)bs[tid]);
        atomicAdd(&stats[80 + tid], (double)bq[tid]);
    }
}

// ---------------- K6: BN2+ReLU on read, 3x3 conv 16->1, sigmoid ----------------
// image split into top/bottom halves: grid 8192, 31-float row stride staggers banks
__global__ __launch_bounds__(256) void k6_conv(
    const float* __restrict__ c2raw, const float* __restrict__ cw,
    const float* __restrict__ cbias, const float* __restrict__ bn,
    float* __restrict__ out)
{
    __shared__ float x_s[16*31*16];     // [16 rows][31 col-slots][16 ch] 31 KiB
    __shared__ float w_s[144];          // [khw=9][ic=16]

    const int tid  = threadIdx.x;
    const int b    = blockIdx.x >> 1;
    const int half = blockIdx.x & 1;
    const int r0   = half*14 - 1;       // first staged input row (may be -1)

    for (int i = tid; i < 16*31*16; i += 256) x_s[i] = 0.f;
    if (tid < 144) {
        int ic = tid / 9, khw = tid - ic*9;   // cw is [ic=16][kh][kw]
        w_s[khw*16 + ic] = cw[tid];
    }
    __syncthreads();

    const float* cr = c2raw + (long long)b*12544;
    for (int i = tid; i < 7168; i += 256) {
        int c = i / 448, rem = i - c*448;
        int rr = rem / 28, iw = rem - rr*28;
        int ih = r0 + rr;
        if ((unsigned)ih < 28u) {
            float v = fmaxf(fmaf(cr[c*784 + ih*28 + iw], bn[64 + c], bn[80 + c]), 0.f);
            x_s[(rr*31 + (iw+1))*16 + c] = v;
        }
    }
    __syncthreads();

    const float bias = cbias[0];
    for (int pass = 0; pass < 2; ++pass) {
        int px = tid + (pass << 8);
        if (px >= 392) break;
        int ohl = px / 28, ow = px - ohl*28;
        float a0=0.f,a1=0.f,a2=0.f,a3=0.f;
        #pragma unroll
        for (int kh = 0; kh < 3; ++kh) {
            #pragma unroll
            for (int kw = 0; kw < 3; ++kw) {
                const float4* xv = (const float4*)&x_s[((ohl+kh)*31 + ow+kw)*16];
                const float4* wv = (const float4*)&w_s[((kh*3 + kw) << 4)];
                #pragma unroll
                for (int c4 = 0; c4 < 4; ++c4) {
                    float4 xx = xv[c4];
                    float4 ww = wv[c4];
                    a0 = fmaf(xx.x, ww.x, a0);
                    a1 = fmaf(xx.y, ww.y, a1);
                    a2 = fmaf(xx.z, ww.z, a2);
                    a3 = fmaf(xx.w, ww.w, a3);
                }
            }
        }
        float t = ((a0+a1) + (a2+a3)) + bias;
        out[(long long)b*784 + (half*14 + ohl)*28 + ow] = 1.f / (1.f + expf(-t));
    }
}

// ---------------- launch ----------------
extern "C" void kernel_launch(void* const* d_in, const int* in_sizes, int n_in,
                              void* d_out, int out_size, void* d_ws, size_t ws_size,
                              hipStream_t stream) {
    const int*   x    = (const int*)d_in[0];
    const float* encW = (const float*)d_in[1];
    const float* emb  = (const float*)d_in[2];
    const float* w1   = (const float*)d_in[3];
    const float* b1   = (const float*)d_in[4];
    const float* g1   = (const float*)d_in[5];
    const float* be1  = (const float*)d_in[6];
    const float* w2   = (const float*)d_in[7];
    const float* b2   = (const float*)d_in[8];
    const float* g2   = (const float*)d_in[9];
    const float* be2  = (const float*)d_in[10];
    const float* cw   = (const float*)d_in[11];
    const float* cb   = (const float*)d_in[12];
    float* out = (float*)d_out;

    char* ws = (char*)d_ws;
    float*  c1raw = (float*)(ws + WS_C1);
    float*  c2raw = (float*)(ws + WS_C2);
    double* stats = (double*)(ws + WS_ST);
    float*  bn    = (float*)(ws + WS_BN);
    float*  w1t   = (float*)(ws + WS_W1T);
    float*  w2t   = (float*)(ws + WS_W2T);

    k_zero<<<1, 128, 0, stream>>>(stats);
    k_prep<<<128, 256, 0, stream>>>(w1, w2, w1t, w2t);
    k1_encode<<<784, 256, 0, stream>>>(x, encW, emb, out);
    k2_deconv1<<<4096, 256, 0, stream>>>(out + ZQ_OFF, w1t, b1, c1raw, stats);
    k_bnfin<<<1, 64, 0, stream>>>(stats, g1, be1, bn, 0, 0, 32, 4096.0*196.0);
    k4_deconv2<<<4096, 256, 0, stream>>>(c1raw, w2t, b2, bn, c2raw, stats);
    k_bnfin<<<1, 64, 0, stream>>>(stats, g2, be2, bn, 64, 64, 16, 4096.0*784.0);
    k6_conv<<<8192, 256, 0, stream>>>(c2raw, cw, cb, bn, out);
}

// Round 6
// 1608.013 us; speedup vs baseline: 2.8285x; 1.1620x over previous
//
#include <hip/hip_runtime.h>
#include <hip/hip_bf16.h>
#include <math.h>

// ---------------- problem constants ----------------
#define BATCH   4096
#define CH      64          // latent channels
#define KCB     512         // codebook size

// d_out layout (floats): x_tilde [4096,1,28,28], z_e_x [4096,64,7,7], z_q_x [4096,64,7,7]
#define XT_N    (BATCH*784)
#define ZE_OFF  (XT_N)
#define ZQ_OFF  (XT_N + BATCH*3136)

// workspace layout (bytes)
#define WS_C1   0                       // conv1 raw: 4096*32*196 floats = 102,760,448 B
#define WS_C2   102760448ULL            // conv2 raw: 4096*16*784 floats = 205,520,896 B
#define WS_ST   308281344ULL            // stats: double sum1[32] sq1[32] sum2[16] sq2[16]
#define WS_BN   308282112ULL            // bn params: float s1[32] h1[32] s2[16] h2[16]
#define WS_W2T  308282496ULL            // w2 transposed [16 taps][32 ic][16 oc] = 32 KiB
// w1t lives in the head of the C2 region: written by prep, read by k2, clobbered by k4 (safe: stream order)
#define WS_W1T  WS_C2

// ---------------- K0: zero the stats accumulators ----------------
__global__ void k_zero(double* __restrict__ stats) {
    int t = threadIdx.x;
    if (t < 96) stats[t] = 0.0;
}

// ---------------- prep: transpose weights for scalar-load access ----------------
// w1 [ic64][oc32][kh][kw] -> w1t [(kh*4+kw)*64+ic][oc32]
// w2 [ic32][oc16][kh][kw] -> w2t [(kh*4+kw)*32+ic][oc16]
__global__ void k_prep(const float* __restrict__ w1, const float* __restrict__ w2,
                       float* __restrict__ w1t, float* __restrict__ w2t) {
    int t = threadIdx.x + blockIdx.x * 256;
    if (t < 32768) {
        int ic = t >> 9, oc = (t >> 4) & 31, khw = t & 15;
        w1t[(khw * 64 + ic) * 32 + oc] = w1[t];
    }
    if (t < 8192) {
        int ic = t >> 8, oc = (t >> 4) & 15, khw = t & 15;
        w2t[(khw * 32 + ic) * 16 + oc] = w2[t];
    }
}

// ---------------- K1: gather + VQ argmin + z_e_x/z_q_x ----------------
__global__ __launch_bounds__(256) void k1_encode(
    const int* __restrict__ xidx, const float* __restrict__ encW,
    const float* __restrict__ emb, float* __restrict__ out)
{
    __shared__ float ee_s[KCB];
    const int tid = threadIdx.x;

    for (int k = tid; k < KCB; k += 256) {
        const float* e = emb + (k << 6);
        float s = 0.f;
        #pragma unroll
        for (int c = 0; c < CH; ++c) s = fmaf(e[c], e[c], s);
        ee_s[k] = s;
    }
    __syncthreads();

    const int p  = blockIdx.x*256 + tid;     // < 200704 exactly
    const int b  = p / 49;
    const int hw = p - b*49;
    const long long row = xidx[b];
    const float* rp = encW + row*3136LL + hw;
    float* zep = out + ZE_OFF + (long long)b*3136 + hw;

    float z[CH];
    float zz = 0.f;
    #pragma unroll
    for (int c = 0; c < CH; ++c) {
        float v = rp[c*49];
        z[c] = v;
        zep[c*49] = v;                       // z_e_x is an exact row copy
        zz = fmaf(v, v, zz);
    }

    float d0 = 3.4e38f, d1 = 3.4e38f;
    int k0 = 0, k1i = 1;
    for (int k = 0; k < KCB; k += 2) {
        const float4* ea4 = (const float4*)(emb + (k << 6));      // uniform -> s_load
        const float4* eb4 = (const float4*)(emb + (k << 6) + 64); // uniform -> s_load
        float a0=0.f,a1=0.f,a2=0.f,a3=0.f, c0=0.f,c1=0.f,c2=0.f,c3=0.f;
        #pragma unroll
        for (int j = 0; j < 16; ++j) {
            float4 ea = ea4[j];
            float4 eb = eb4[j];
            a0 = fmaf(z[4*j+0], ea.x, a0);
            a1 = fmaf(z[4*j+1], ea.y, a1);
            a2 = fmaf(z[4*j+2], ea.z, a2);
            a3 = fmaf(z[4*j+3], ea.w, a3);
            c0 = fmaf(z[4*j+0], eb.x, c0);
            c1 = fmaf(z[4*j+1], eb.y, c1);
            c2 = fmaf(z[4*j+2], eb.z, c2);
            c3 = fmaf(z[4*j+3], eb.w, c3);
        }
        float dotA = (a0+a1) + (a2+a3);
        float dotB = (c0+c1) + (c2+c3);
        float dA = (zz - 2.f*dotA) + ee_s[k];
        float dB = (zz - 2.f*dotB) + ee_s[k+1];
        if (dA < d0)      { d1 = d0; k1i = k0; d0 = dA; k0 = k; }
        else if (dA < d1) { d1 = dA; k1i = k; }
        if (dB < d0)      { d1 = d0; k1i = k0; d0 = dB; k0 = k+1; }
        else if (dB < d1) { d1 = dB; k1i = k+1; }
    }

    // fp64 refine of near-ties -> effectively exact argmin
    if (d1 - d0 < fmaxf(1e-6f, 1e-3f * fabsf(d0))) {
        double D0 = 0.0, D1 = 0.0;
        #pragma unroll
        for (int c = 0; c < CH; ++c) {
            double f0 = (double)z[c] - (double)emb[k0*CH + c];
            double f1 = (double)z[c] - (double)emb[k1i*CH + c];
            D0 += f0*f0; D1 += f1*f1;
        }
        if (D1 < D0 || (D1 == D0 && k1i < k0)) k0 = k1i;
    }

    float* zqp = out + ZQ_OFF + (long long)b*3136 + hw;
    const float* e0 = emb + k0*CH;
    #pragma unroll
    for (int c = 0; c < CH; ++c) zqp[c*49] = e0[c];
}

#define OC8(A, xc, wr) { \
    (A)[0]=fmaf((xc),(wr)[0],(A)[0]); (A)[1]=fmaf((xc),(wr)[1],(A)[1]); \
    (A)[2]=fmaf((xc),(wr)[2],(A)[2]); (A)[3]=fmaf((xc),(wr)[3],(A)[3]); \
    (A)[4]=fmaf((xc),(wr)[4],(A)[4]); (A)[5]=fmaf((xc),(wr)[5],(A)[5]); \
    (A)[6]=fmaf((xc),(wr)[6],(A)[6]); (A)[7]=fmaf((xc),(wr)[7],(A)[7]); }

// ---------------- K2: deconv1 (64->32, 7->14) + bias, BN1 stats ----------------
// 1 image per block; wave -> 8 oc; lanes -> 49 base pixels; pw-paired float2 stores
__global__ __launch_bounds__(256) void k2_deconv1(
    const float* __restrict__ zq, const float* __restrict__ w1t,
    const float* __restrict__ b1, float* __restrict__ c1raw,
    double* __restrict__ stats)
{
    __shared__ float x_s[81*64];        // XOR-swizzled [9x9 rows][64ch], 20.25 KiB
    __shared__ float bs[32], bq[32];

    const int tid  = threadIdx.x;
    const int wave = tid >> 6;
    const int lane = tid & 63;
    const int b    = blockIdx.x;

    for (int i = tid; i < 81*64; i += 256) x_s[i] = 0.f;
    if (tid < 32) { bs[tid] = 0.f; bq[tid] = 0.f; }
    __syncthreads();

    const float* zb = zq + (long long)b*3136;
    for (int i = tid; i < 3136; i += 256) {
        int c = i / 49, hw = i - c*49;
        int ih = hw / 7, iw = hw - ih*7;
        int r = (ih+1)*9 + (iw+1);
        int slot = (c >> 2) ^ (r & 7);
        x_s[r*64 + (slot << 2) + (c & 3)] = zb[i];
    }
    __syncthreads();

    const int oc0u = __builtin_amdgcn_readfirstlane(wave << 3);
    float bias[8];
    #pragma unroll
    for (int j = 0; j < 8; ++j) bias[j] = b1[oc0u + j];

    const bool act = lane < 49;
    const int  la  = act ? lane : 0;
    const int  a   = la / 7;
    const int  bb  = la - a*7;

    float ts[8], tq[8];
    #pragma unroll
    for (int j = 0; j < 8; ++j) { ts[j] = 0.f; tq[j] = 0.f; }

    float* c1b = c1raw + (long long)b*6272;

    #pragma unroll
    for (int ph = 0; ph < 2; ++ph) {
        float acc[2][8];
        #pragma unroll
        for (int pw = 0; pw < 2; ++pw) {
            #pragma unroll
            for (int j = 0; j < 8; ++j) acc[pw][j] = 0.f;
            #pragma unroll
            for (int dh = 0; dh < 2; ++dh) {
                #pragma unroll
                for (int dw = 0; dw < 2; ++dw) {
                    const int ih = a + ph - dh, iw = bb + pw - dw;
                    const int r  = (ih+1)*9 + (iw+1);
                    const int rx = r & 7;
                    const int rbase = r*64;
                    const int kh = (1-ph) + 2*dh, kw = (1-pw) + 2*dw;
                    const float* wb = w1t + (((kh<<2)+kw) << 11) + oc0u;   // uniform
                    #pragma unroll
                    for (int ic4 = 0; ic4 < 16; ++ic4) {
                        const float4 xv = *(const float4*)&x_s[rbase + ((ic4 ^ rx) << 2)];
                        const float* wr = wb + (ic4 << 7);                  // uniform
                        OC8(acc[pw], xv.x, wr); OC8(acc[pw], xv.y, wr+32);
                        OC8(acc[pw], xv.z, wr+64); OC8(acc[pw], xv.w, wr+96);
                    }
                }
            }
        }
        if (act) {
            const int off = (2*a + ph)*14 + 2*bb;
            #pragma unroll
            for (int j = 0; j < 8; ++j) {
                float v0 = acc[0][j] + bias[j];
                float v1 = acc[1][j] + bias[j];
                *(float2*)&c1b[(oc0u + j)*196 + off] = make_float2(v0, v1);
                ts[j] += v0 + v1;
                tq[j] = fmaf(v0, v0, tq[j]); tq[j] = fmaf(v1, v1, tq[j]);
            }
        }
    }

    #pragma unroll
    for (int j = 0; j < 8; ++j) {
        atomicAdd(&bs[oc0u + j], ts[j]);
        atomicAdd(&bq[oc0u + j], tq[j]);
    }
    __syncthreads();
    if (tid < 32) {
        atomicAdd(&stats[tid],      (double)bs[tid]);
        atomicAdd(&stats[32 + tid], (double)bq[tid]);
    }
}

// ---------------- K3/K5: fold BN stats into scale/shift ----------------
__global__ void k_bnfin(const double* __restrict__ stats, const float* __restrict__ g,
                        const float* __restrict__ be, float* __restrict__ bn,
                        int soff, int boff, int nch, double n)
{
    int t = threadIdx.x;
    if (t < nch) {
        double mean = stats[soff + t] / n;
        double var  = stats[soff + nch + t] / n - mean*mean;
        double rstd = 1.0 / sqrt(var + 1e-5);
        double sc   = (double)g[t] * rstd;
        bn[boff + t]       = (float)sc;
        bn[boff + nch + t] = (float)((double)be[t] - mean*sc);
    }
}

// ---------------- K4: BN1+ReLU on read, deconv2 (32->16, 14->28), BN2 stats ----------------
// HALF-IMAGE per block (grid 8192): LDS 18 KiB -> 8 blocks/CU -> 32 waves/CU.
// Round-2 compute structure kept (cls-sequential, single acc[8], scalar stores,
// VGPR ~52). Do NOT pair pw / double accumulators (r3/r4: VGPR 172, 12% occ).
__global__ __launch_bounds__(256) void k4_deconv2(
    const float* __restrict__ c1raw, const float* __restrict__ w2t,
    const float* __restrict__ b2, const float* __restrict__ bn,
    float* __restrict__ c2raw, double* __restrict__ stats)
{
    __shared__ float x_s[9*16*32];      // XOR-swizzled [9 rows][16 cols][32 ch], 18 KiB
    __shared__ float bs[16], bq[16];

    const int tid  = threadIdx.x;
    const int wave = tid >> 6;
    const int lane = tid & 63;
    const int b    = blockIdx.x >> 1;
    const int half = blockIdx.x & 1;     // output rows [half*14, half*14+14)
    const int ib0  = half*7 - 1;         // first staged input row (may be -1)

    for (int i = tid; i < 9*16*32; i += 256) x_s[i] = 0.f;
    if (tid < 16) { bs[tid] = 0.f; bq[tid] = 0.f; }
    __syncthreads();

    const float* cb = c1raw + (long long)b*6272;
    for (int i = tid; i < 4032; i += 256) {           // 32 ic x 9 rows x 14 cols
        int ic = i / 126, rem = i - ic*126;
        int lr = rem / 14, iw = rem - lr*14;
        int ih = ib0 + lr;
        if ((unsigned)ih < 14u) {
            float v = fmaxf(fmaf(cb[ic*196 + ih*14 + iw], bn[ic], bn[32 + ic]), 0.f);
            int r = lr*16 + (iw+1);
            int slot = (ic >> 2) ^ (r & 7);
            x_s[r*32 + (slot << 2) + (ic & 3)] = v;
        }
    }
    __syncthreads();

    const int oc0u   = __builtin_amdgcn_readfirstlane((wave & 1) << 3);
    const int pxhalf = wave >> 1;
    float bias[8];
    #pragma unroll
    for (int j = 0; j < 8; ++j) bias[j] = b2[oc0u + j];

    const bool act = lane < 49;
    const int  q   = pxhalf*49 + (act ? lane : 0);    // 0..97: base px in this half
    const int  al  = q / 14;                          // local base row 0..6
    const int  bb  = q - al*14;

    float ts[8], tq[8];
    #pragma unroll
    for (int j = 0; j < 8; ++j) { ts[j] = 0.f; tq[j] = 0.f; }

    float* c2b = c2raw + (long long)b*12544;

    for (int cls = 0; cls < 4; ++cls) {
        const int ph = cls >> 1, pw = cls & 1;
        const int oh = (half*7 + al)*2 + ph, ow = 2*bb + pw;
        float acc[8];
        #pragma unroll
        for (int j = 0; j < 8; ++j) acc[j] = 0.f;
        #pragma unroll
        for (int dh = 0; dh < 2; ++dh) {
            #pragma unroll
            for (int dw = 0; dw < 2; ++dw) {
                const int lr = al + ph - dh + 1;      // staged row 0..8
                const int iw = bb + pw - dw;
                const int r  = lr*16 + (iw+1);
                const int rx = r & 7;
                const int rbase = r*32;
                const int kh = (1-ph) + 2*dh, kw = (1-pw) + 2*dw;
                const float* wb = w2t + (((kh<<2)+kw) << 9) + oc0u;    // uniform
                #pragma unroll
                for (int ic4 = 0; ic4 < 8; ++ic4) {
                    const float4 xv = *(const float4*)&x_s[rbase + ((ic4 ^ rx) << 2)];
                    const float* wr = wb + (ic4 << 6);                  // uniform
                    OC8(acc, xv.x, wr); OC8(acc, xv.y, wr+16);
                    OC8(acc, xv.z, wr+32); OC8(acc, xv.w, wr+48);
                }
            }
        }
        if (act) {
            float* cp = c2b + oh*28 + ow;
            #pragma unroll
            for (int j = 0; j < 8; ++j) {
                float v = acc[j] + bias[j];
                cp[(oc0u + j)*784] = v;
                ts[j] += v; tq[j] = fmaf(v, v, tq[j]);
            }
        }
    }

    #pragma unroll
    for (int j = 0; j < 8; ++j) {
        atomicAdd(&bs[oc0u + j], ts[j]);
        atomicAdd(&bq[oc0u + j], tq[j]);
    }
    __syncthreads();
    if (tid < 16) {
        atomicAdd(&stats[64 + tid], (double)bs[tid]);
        atomicAdd(&stats[80 + tid], (double)bq[tid]);
    }
}

// ---------------- K6: BN2+ReLU on read, 3x3 conv 16->1, sigmoid ----------------
// QUARTER-image per block (grid 16384): LDS 17.4 KiB -> 8 blocks/CU.
__global__ __launch_bounds__(256) void k6_conv(
    const float* __restrict__ c2raw, const float* __restrict__ cw,
    const float* __restrict__ cbias, const float* __restrict__ bn,
    float* __restrict__ out)
{
    __shared__ float x_s[9*31*16];      // [9 rows][31 col-slots][16 ch] 17.4 KiB
    __shared__ float w_s[144];          // [khw=9][ic=16]

    const int tid  = threadIdx.x;
    const int b    = blockIdx.x >> 2;
    const int qrt  = blockIdx.x & 3;    // output rows [qrt*7, qrt*7+7)
    const int r0   = qrt*7 - 1;         // first staged input row (may be -1)

    for (int i = tid; i < 9*31*16; i += 256) x_s[i] = 0.f;
    if (tid < 144) {
        int ic = tid / 9, khw = tid - ic*9;   // cw is [ic=16][kh][kw]
        w_s[khw*16 + ic] = cw[tid];
    }
    __syncthreads();

    const float* cr = c2raw + (long long)b*12544;
    for (int i = tid; i < 4032; i += 256) {           // 16 ch x 9 rows x 28 cols
        int c = i / 252, rem = i - c*252;
        int rr = rem / 28, iw = rem - rr*28;
        int ih = r0 + rr;
        if ((unsigned)ih < 28u) {
            float v = fmaxf(fmaf(cr[c*784 + ih*28 + iw], bn[64 + c], bn[80 + c]), 0.f);
            x_s[(rr*31 + (iw+1))*16 + c] = v;
        }
    }
    __syncthreads();

    const float bias = cbias[0];
    const int px = tid;
    if (px < 196) {
        int ohl = px / 28, ow = px - ohl*28;
        float a0=0.f,a1=0.f,a2=0.f,a3=0.f;
        #pragma unroll
        for (int kh = 0; kh < 3; ++kh) {
            #pragma unroll
            for (int kw = 0; kw < 3; ++kw) {
                const float4* xv = (const float4*)&x_s[((ohl+kh)*31 + ow+kw)*16];
                const float4* wv = (const float4*)&w_s[((kh*3 + kw) << 4)];
                #pragma unroll
                for (int c4 = 0; c4 < 4; ++c4) {
                    float4 xx = xv[c4];
                    float4 ww = wv[c4];
                    a0 = fmaf(xx.x, ww.x, a0);
                    a1 = fmaf(xx.y, ww.y, a1);
                    a2 = fmaf(xx.z, ww.z, a2);
                    a3 = fmaf(xx.w, ww.w, a3);
                }
            }
        }
        float t = ((a0+a1) + (a2+a3)) + bias;
        out[(long long)b*784 + (qrt*7 + ohl)*28 + ow] = 1.f / (1.f + expf(-t));
    }
}

// ---------------- launch ----------------
extern "C" void kernel_launch(void* const* d_in, const int* in_sizes, int n_in,
                              void* d_out, int out_size, void* d_ws, size_t ws_size,
                              hipStream_t stream) {
    const int*   x    = (const int*)d_in[0];
    const float* encW = (const float*)d_in[1];
    const float* emb  = (const float*)d_in[2];
    const float* w1   = (const float*)d_in[3];
    const float* b1   = (const float*)d_in[4];
    const float* g1   = (const float*)d_in[5];
    const float* be1  = (const float*)d_in[6];
    const float* w2   = (const float*)d_in[7];
    const float* b2   = (const float*)d_in[8];
    const float* g2   = (const float*)d_in[9];
    const float* be2  = (const float*)d_in[10];
    const float* cw   = (const float*)d_in[11];
    const float* cb   = (const float*)d_in[12];
    float* out = (float*)d_out;

    char* ws = (char*)d_ws;
    float*  c1raw = (float*)(ws + WS_C1);
    float*  c2raw = (float*)(ws + WS_C2);
    double* stats = (double*)(ws + WS_ST);
    float*  bn    = (float*)(ws + WS_BN);
    float*  w1t   = (float*)(ws + WS_W1T);
    float*  w2t   = (float*)(ws + WS_W2T);

    k_zero<<<1, 128, 0, stream>>>(stats);
    k_prep<<<128, 256, 0, stream>>>(w1, w2, w1t, w2t);
    k1_encode<<<784, 256, 0, stream>>>(x, encW, emb, out);
    k2_deconv1<<<4096, 256, 0, stream>>>(out + ZQ_OFF, w1t, b1, c1raw, stats);
    k_bnfin<<<1, 64, 0, stream>>>(stats, g1, be1, bn, 0, 0, 32, 4096.0*196.0);
    k4_deconv2<<<8192, 256, 0, stream>>>(c1raw, w2t, b2, bn, c2raw, stats);
    k_bnfin<<<1, 64, 0, stream>>>(stats, g2, be2, bn, 64, 64, 16, 4096.0*784.0);
    k6_conv<<<16384, 256, 0, stream>>>(c2raw, cw, cb, bn, out);
}

// Round 7
// 717.596 us; speedup vs baseline: 6.3381x; 2.2408x over previous
//
#include <hip/hip_runtime.h>
#include <hip/hip_bf16.h>
#include <math.h>

// ---------------- problem constants ----------------
#define BATCH   4096
#define CH      64          // latent channels
#define KCB     512         // codebook size

// d_out layout (floats): x_tilde [4096,1,28,28], z_e_x [4096,64,7,7], z_q_x [4096,64,7,7]
#define XT_N    (BATCH*784)
#define ZE_OFF  (XT_N)
#define ZQ_OFF  (XT_N + BATCH*3136)

// workspace layout (bytes)
// c1cls: [4096][4 cls][32 oc][49 px] fp32 = 102,760,448 B
// c2cls: [4096][4 cls][16 oc][196 px] fp32 = 205,520,896 B
#define WS_C1   0
#define WS_C2   102760448ULL
#define WS_ST   308281344ULL            // stats: double sum1[32] sq1[32] sum2[16] sq2[16]
#define WS_BN   308282112ULL            // bn params: float s1[32] h1[32] s2[16] h2[16]
#define WS_WF2  308282496ULL            // w2 MFMA frags bf16: 16 frags x 64 lanes x 16B = 16 KiB
// w1 frags (64 KiB) live at the head of the C2 region: written by prep, read by k2,
// clobbered by k4's c2 writes (safe: stream order).
#define WS_WF1  WS_C2

typedef __attribute__((ext_vector_type(8))) __bf16 bf16x8;
typedef __attribute__((ext_vector_type(4))) float f32x4;
union B8 { uint4 u; bf16x8 v; };

__device__ inline unsigned short f2bf(float f) {   // RNE fp32->bf16
    unsigned int u = __float_as_uint(f);
    u = u + 0x7fffu + ((u >> 16) & 1u);
    return (unsigned short)(u >> 16);
}

// ---------------- K0: zero the stats accumulators ----------------
__global__ void k_zero(double* __restrict__ stats) {
    int t = threadIdx.x;
    if (t < 96) stats[t] = 0.0;
}

// ---------------- prep: pack weights into per-lane MFMA A-fragments (bf16) ----------
// Slot rule (MUST match the x-side B-frag reads): lane l, element i -> ic = icbase + 8*(l>>4) + i.
// This same (group,elem)->ic rule on both operands makes the contraction correct for any
// hardware k-permutation.
// w1 [ic64][oc32][kh4][kw4]; frag id = cls*16 + tap*4 + khalf*2 + mt  (64 frags)
// w2 [ic32][oc16][kh4][kw4]; frag id = cls*4 + tap                    (16 frags)
__global__ void k_prep(const float* __restrict__ w1, const float* __restrict__ w2,
                       unsigned short* __restrict__ w1f, unsigned short* __restrict__ w2f) {
    int t = threadIdx.x + blockIdx.x * 256;     // 0..32767
    {
        int i = t & 7, lane = (t >> 3) & 63, frag = t >> 9;
        int cls = frag >> 4, tap = (frag >> 2) & 3, khalf = (frag >> 1) & 1, mt = frag & 1;
        int ph = cls >> 1, pw = cls & 1, dh = tap >> 1, dw = tap & 1;
        int kh = (1 - ph) + 2 * dh, kw = (1 - pw) + 2 * dw;
        int oc = mt * 16 + (lane & 15);
        int ic = khalf * 32 + ((lane >> 4) << 3) + i;
        w1f[t] = f2bf(w1[((ic * 32 + oc) << 4) + kh * 4 + kw]);
    }
    if (t < 8192) {
        int i = t & 7, lane = (t >> 3) & 63, frag = t >> 9;   // frag < 16
        int cls = frag >> 2, tap = frag & 3;
        int ph = cls >> 1, pw = cls & 1, dh = tap >> 1, dw = tap & 1;
        int kh = (1 - ph) + 2 * dh, kw = (1 - pw) + 2 * dw;
        int oc = lane & 15;
        int ic = ((lane >> 4) << 3) + i;
        w2f[t] = f2bf(w2[((ic * 16 + oc) << 4) + kh * 4 + kw]);
    }
}

// ---------------- K1: gather + VQ argmin + z_e_x/z_q_x (fp32, unchanged) ------------
__global__ __launch_bounds__(256) void k1_encode(
    const int* __restrict__ xidx, const float* __restrict__ encW,
    const float* __restrict__ emb, float* __restrict__ out)
{
    __shared__ float ee_s[KCB];
    const int tid = threadIdx.x;

    for (int k = tid; k < KCB; k += 256) {
        const float* e = emb + (k << 6);
        float s = 0.f;
        #pragma unroll
        for (int c = 0; c < CH; ++c) s = fmaf(e[c], e[c], s);
        ee_s[k] = s;
    }
    __syncthreads();

    const int p  = blockIdx.x*256 + tid;     // < 200704 exactly
    const int b  = p / 49;
    const int hw = p - b*49;
    const long long row = xidx[b];
    const float* rp = encW + row*3136LL + hw;
    float* zep = out + ZE_OFF + (long long)b*3136 + hw;

    float z[CH];
    float zz = 0.f;
    #pragma unroll
    for (int c = 0; c < CH; ++c) {
        float v = rp[c*49];
        z[c] = v;
        zep[c*49] = v;                       // z_e_x is an exact row copy
        zz = fmaf(v, v, zz);
    }

    float d0 = 3.4e38f, d1 = 3.4e38f;
    int k0 = 0, k1i = 1;
    for (int k = 0; k < KCB; k += 2) {
        const float4* ea4 = (const float4*)(emb + (k << 6));      // uniform -> s_load
        const float4* eb4 = (const float4*)(emb + (k << 6) + 64); // uniform -> s_load
        float a0=0.f,a1=0.f,a2=0.f,a3=0.f, c0=0.f,c1=0.f,c2=0.f,c3=0.f;
        #pragma unroll
        for (int j = 0; j < 16; ++j) {
            float4 ea = ea4[j];
            float4 eb = eb4[j];
            a0 = fmaf(z[4*j+0], ea.x, a0);
            a1 = fmaf(z[4*j+1], ea.y, a1);
            a2 = fmaf(z[4*j+2], ea.z, a2);
            a3 = fmaf(z[4*j+3], ea.w, a3);
            c0 = fmaf(z[4*j+0], eb.x, c0);
            c1 = fmaf(z[4*j+1], eb.y, c1);
            c2 = fmaf(z[4*j+2], eb.z, c2);
            c3 = fmaf(z[4*j+3], eb.w, c3);
        }
        float dotA = (a0+a1) + (a2+a3);
        float dotB = (c0+c1) + (c2+c3);
        float dA = (zz - 2.f*dotA) + ee_s[k];
        float dB = (zz - 2.f*dotB) + ee_s[k+1];
        if (dA < d0)      { d1 = d0; k1i = k0; d0 = dA; k0 = k; }
        else if (dA < d1) { d1 = dA; k1i = k; }
        if (dB < d0)      { d1 = d0; k1i = k0; d0 = dB; k0 = k+1; }
        else if (dB < d1) { d1 = dB; k1i = k+1; }
    }

    if (d1 - d0 < fmaxf(1e-6f, 1e-3f * fabsf(d0))) {
        double D0 = 0.0, D1 = 0.0;
        #pragma unroll
        for (int c = 0; c < CH; ++c) {
            double f0 = (double)z[c] - (double)emb[k0*CH + c];
            double f1 = (double)z[c] - (double)emb[k1i*CH + c];
            D0 += f0*f0; D1 += f1*f1;
        }
        if (D1 < D0 || (D1 == D0 && k1i < k0)) k0 = k1i;
    }

    float* zqp = out + ZQ_OFF + (long long)b*3136 + hw;
    const float* e0 = emb + k0*CH;
    #pragma unroll
    for (int c = 0; c < CH; ++c) zqp[c*49] = e0[c];
}

// ---------------- K2: deconv1 via MFMA (64->32, 7->14) + bias, BN1 stats ------------
// 2 images/block, wave = parity class. A=weights (M=32 oc, 2 tiles), B=x (N=px), K=4taps*64ic.
// x in LDS bf16, row stride 144B (9x16B) -> <=2-way bank alias (free).
__global__ __launch_bounds__(256) void k2_deconv1(
    const float* __restrict__ zq, const unsigned short* __restrict__ w1f,
    const float* __restrict__ b1, float* __restrict__ c1cls,
    double* __restrict__ stats)
{
    __shared__ __align__(16) unsigned short x_s[2*81*72]; // [img][r<81][72 bf16] 23.3 KiB
    __shared__ float bs[32], bq[32];

    const int tid = threadIdx.x, wave = tid >> 6, lane = tid & 63;
    const int b0 = blockIdx.x << 1;

    for (int i = tid; i < 2*81*72/2; i += 256) ((unsigned int*)x_s)[i] = 0u;
    if (tid < 32) { bs[tid] = 0.f; bq[tid] = 0.f; }
    __syncthreads();

    for (int i = tid; i < 6272; i += 256) {
        int img = i >= 3136;
        int e = i - img*3136;
        int c = e / 49, hw = e - c*49;
        int ih = hw / 7, iw = hw - ih*7;
        float v = zq[(long long)(b0+img)*3136 + e];
        x_s[img*5832 + ((ih+1)*9 + (iw+1))*72 + c] = f2bf(v);
    }
    __syncthreads();

    const int cls = wave, ph = cls >> 1, pw = cls & 1;
    bf16x8 wfr[4][2][2];   // [tap][khalf][mtile]
    {
        const uint4* wp = (const uint4*)w1f + (cls*16)*64 + lane;
        #pragma unroll
        for (int tap = 0; tap < 4; ++tap)
            #pragma unroll
            for (int kh2 = 0; kh2 < 2; ++kh2)
                #pragma unroll
                for (int mt = 0; mt < 2; ++mt) {
                    B8 t; t.u = wp[(tap*4 + kh2*2 + mt)*64];
                    wfr[tap][kh2][mt] = t.v;
                }
    }
    float biasv[2][4];
    #pragma unroll
    for (int mt = 0; mt < 2; ++mt)
        #pragma unroll
        for (int rg = 0; rg < 4; ++rg)
            biasv[mt][rg] = b1[mt*16 + ((lane >> 4) << 2) + rg];

    float ts[2][4] = {{0.f}}, tq[2][4] = {{0.f}};
    const int gb = (lane >> 4) << 4;    // 16B granule for this lane's k-group

    for (int nt = 0; nt < 7; ++nt) {    // 7 N-tiles cover 98 px (2 img x 49)
        int m = nt*16 + (lane & 15);
        bool valid = m < 98;
        int mm = valid ? m : 0;
        int img = mm >= 49;
        int px = mm - img*49;
        int a = px / 7, bb = px - a*7;
        f32x4 acc0 = {0.f,0.f,0.f,0.f}, acc1 = {0.f,0.f,0.f,0.f};
        #pragma unroll
        for (int dh = 0; dh < 2; ++dh)
            #pragma unroll
            for (int dw = 0; dw < 2; ++dw) {
                int tap = dh*2 + dw;
                int r = (a + ph - dh + 1)*9 + (bb + pw - dw + 1);
                const char* p = (const char*)x_s + img*11664 + r*144 + gb;
                B8 x0; x0.u = *(const uint4*)p;          // ic 0..31 slice
                B8 x1; x1.u = *(const uint4*)(p + 64);   // ic 32..63 slice
                acc0 = __builtin_amdgcn_mfma_f32_16x16x32_bf16(wfr[tap][0][0], x0.v, acc0, 0,0,0);
                acc1 = __builtin_amdgcn_mfma_f32_16x16x32_bf16(wfr[tap][0][1], x0.v, acc1, 0,0,0);
                acc0 = __builtin_amdgcn_mfma_f32_16x16x32_bf16(wfr[tap][1][0], x1.v, acc0, 0,0,0);
                acc1 = __builtin_amdgcn_mfma_f32_16x16x32_bf16(wfr[tap][1][1], x1.v, acc1, 0,0,0);
            }
        if (valid) {
            float* base = c1cls + (long long)(b0+img)*6272 + cls*1568 + px;
            #pragma unroll
            for (int rg = 0; rg < 4; ++rg) {
                int oc = ((lane >> 4) << 2) + rg;
                float v0 = acc0[rg] + biasv[0][rg];
                float v1 = acc1[rg] + biasv[1][rg];
                base[oc*49]      = v0;
                base[(oc+16)*49] = v1;
                ts[0][rg] += v0; tq[0][rg] = fmaf(v0, v0, tq[0][rg]);
                ts[1][rg] += v1; tq[1][rg] = fmaf(v1, v1, tq[1][rg]);
            }
        }
    }

    #pragma unroll
    for (int mt = 0; mt < 2; ++mt)
        #pragma unroll
        for (int rg = 0; rg < 4; ++rg) {
            float s = ts[mt][rg], q = tq[mt][rg];
            #pragma unroll
            for (int msk = 1; msk < 16; msk <<= 1) {
                s += __shfl_xor(s, msk);
                q += __shfl_xor(q, msk);
            }
            if ((lane & 15) == 0) {
                int oc = mt*16 + ((lane >> 4) << 2) + rg;
                atomicAdd(&bs[oc], s);
                atomicAdd(&bq[oc], q);
            }
        }
    __syncthreads();
    if (tid < 32) {
        atomicAdd(&stats[tid],      (double)bs[tid]);
        atomicAdd(&stats[32 + tid], (double)bq[tid]);
    }
}

// ---------------- K3/K5: fold BN stats into scale/shift ----------------
__global__ void k_bnfin(const double* __restrict__ stats, const float* __restrict__ g,
                        const float* __restrict__ be, float* __restrict__ bn,
                        int soff, int boff, int nch, double n)
{
    int t = threadIdx.x;
    if (t < nch) {
        double mean = stats[soff + t] / n;
        double var  = stats[soff + nch + t] / n - mean*mean;
        double rstd = 1.0 / sqrt(var + 1e-5);
        double sc   = (double)g[t] * rstd;
        bn[boff + t]       = (float)sc;
        bn[boff + nch + t] = (float)((double)be[t] - mean*sc);
    }
}

// ---------------- K4: BN1+ReLU on read, deconv2 via MFMA (32->16, 14->28), BN2 stats -
// 1 image/block, wave = parity class. M=16 oc (1 tile), K=32 ic per tap (1 MFMA/tap).
// x LDS bf16 row stride 80B (5x16B) -> <=2-way alias (free).
__global__ __launch_bounds__(256) void k4_deconv2(
    const float* __restrict__ c1cls, const unsigned short* __restrict__ w2f,
    const float* __restrict__ b2, const float* __restrict__ bn,
    float* __restrict__ c2cls, double* __restrict__ stats)
{
    __shared__ __align__(16) unsigned short x_s[256*40];  // [r<256][40 bf16] 20 KiB
    __shared__ float bnl[64];
    __shared__ float bs[16], bq[16];

    const int tid = threadIdx.x, wave = tid >> 6, lane = tid & 63;
    const int b = blockIdx.x;

    for (int i = tid; i < 256*40/2; i += 256) ((unsigned int*)x_s)[i] = 0u;
    if (tid < 64) bnl[tid] = bn[tid];
    if (tid < 16) { bs[tid] = 0.f; bq[tid] = 0.f; }
    __syncthreads();

    const float* cb = c1cls + (long long)b*6272;
    for (int i = tid; i < 6272; i += 256) {   // linear, fully coalesced
        int cl = i / 1568, e = i - cl*1568;
        int ic = e / 49, pxc = e - ic*49;
        int a = pxc / 7, bb = pxc - a*7;
        int ih = 2*a + (cl >> 1), iw = 2*bb + (cl & 1);
        float v = fmaxf(fmaf(cb[i], bnl[ic], bnl[32 + ic]), 0.f);
        x_s[((ih+1)*16 + (iw+1))*40 + ic] = f2bf(v);
    }
    __syncthreads();

    const int cls = wave, ph = cls >> 1, pw = cls & 1;
    bf16x8 wfr[4];
    {
        const uint4* wp = (const uint4*)w2f + (cls*4)*64 + lane;
        #pragma unroll
        for (int tap = 0; tap < 4; ++tap) { B8 t; t.u = wp[tap*64]; wfr[tap] = t.v; }
    }
    float biasv[4];
    #pragma unroll
    for (int rg = 0; rg < 4; ++rg) biasv[rg] = b2[((lane >> 4) << 2) + rg];

    float ts[4] = {0.f}, tq[4] = {0.f};
    float* c2b = c2cls + (long long)b*12544 + cls*3136;
    const int gb = (lane >> 4) << 4;

    for (int nt = 0; nt < 13; ++nt) {    // 13 N-tiles cover 196 px
        int m = nt*16 + (lane & 15);
        bool valid = m < 196;
        int px = valid ? m : 0;
        int a = px / 14, bb = px - a*14;
        f32x4 acc = {0.f,0.f,0.f,0.f};
        #pragma unroll
        for (int dh = 0; dh < 2; ++dh)
            #pragma unroll
            for (int dw = 0; dw < 2; ++dw) {
                int tap = dh*2 + dw;
                int r = (a + ph - dh + 1)*16 + (bb + pw - dw + 1);
                B8 x0; x0.u = *(const uint4*)((const char*)x_s + r*80 + gb);
                acc = __builtin_amdgcn_mfma_f32_16x16x32_bf16(wfr[tap], x0.v, acc, 0,0,0);
            }
        if (valid) {
            float* base = c2b + px;
            #pragma unroll
            for (int rg = 0; rg < 4; ++rg) {
                int oc = ((lane >> 4) << 2) + rg;
                float v = acc[rg] + biasv[rg];
                base[oc*196] = v;
                ts[rg] += v; tq[rg] = fmaf(v, v, tq[rg]);
            }
        }
    }

    #pragma unroll
    for (int rg = 0; rg < 4; ++rg) {
        float s = ts[rg], q = tq[rg];
        #pragma unroll
        for (int msk = 1; msk < 16; msk <<= 1) {
            s += __shfl_xor(s, msk);
            q += __shfl_xor(q, msk);
        }
        if ((lane & 15) == 0) {
            int oc = ((lane >> 4) << 2) + rg;
            atomicAdd(&bs[oc], s);
            atomicAdd(&bq[oc], q);
        }
    }
    __syncthreads();
    if (tid < 16) {
        atomicAdd(&stats[64 + tid], (double)bs[tid]);
        atomicAdd(&stats[80 + tid], (double)bq[tid]);
    }
}

// ---------------- K6: BN2+ReLU on read, 3x3 conv 16->1, sigmoid (fp32) --------------
// QUARTER-image per block (grid 16384); reads class-major c2cls.
__global__ __launch_bounds__(256) void k6_conv(
    const float* __restrict__ c2cls, const float* __restrict__ cw,
    const float* __restrict__ cbias, const float* __restrict__ bn,
    float* __restrict__ out)
{
    __shared__ float x_s[9*31*16];      // [9 rows][31 col-slots][16 ch] 17.4 KiB
    __shared__ float w_s[144];          // [khw=9][ic=16]

    const int tid  = threadIdx.x;
    const int b    = blockIdx.x >> 2;
    const int qrt  = blockIdx.x & 3;    // output rows [qrt*7, qrt*7+7)
    const int r0   = qrt*7 - 1;         // first staged input row (may be -1)

    for (int i = tid; i < 9*31*16; i += 256) x_s[i] = 0.f;
    if (tid < 144) {
        int ic = tid / 9, khw = tid - ic*9;   // cw is [ic=16][kh][kw]
        w_s[khw*16 + ic] = cw[tid];
    }
    __syncthreads();

    const float* cr = c2cls + (long long)b*12544;
    for (int i = tid; i < 4032; i += 256) {           // 16 ch x 9 rows x 28 cols
        int c = i / 252, rem = i - c*252;
        int rr = rem / 28, iw = rem - rr*28;
        int ih = r0 + rr;
        if ((unsigned)ih < 28u) {
            int cl  = ((ih & 1) << 1) | (iw & 1);
            int px2 = (ih >> 1)*14 + (iw >> 1);
            float v = fmaxf(fmaf(cr[cl*3136 + c*196 + px2], bn[64 + c], bn[80 + c]), 0.f);
            x_s[(rr*31 + (iw+1))*16 + c] = v;
        }
    }
    __syncthreads();

    const float bias = cbias[0];
    const int px = tid;
    if (px < 196) {
        int ohl = px / 28, ow = px - ohl*28;
        float a0=0.f,a1=0.f,a2=0.f,a3=0.f;
        #pragma unroll
        for (int kh = 0; kh < 3; ++kh) {
            #pragma unroll
            for (int kw = 0; kw < 3; ++kw) {
                const float4* xv = (const float4*)&x_s[((ohl+kh)*31 + ow+kw)*16];
                const float4* wv = (const float4*)&w_s[((kh*3 + kw) << 4)];
                #pragma unroll
                for (int c4 = 0; c4 < 4; ++c4) {
                    float4 xx = xv[c4];
                    float4 ww = wv[c4];
                    a0 = fmaf(xx.x, ww.x, a0);
                    a1 = fmaf(xx.y, ww.y, a1);
                    a2 = fmaf(xx.z, ww.z, a2);
                    a3 = fmaf(xx.w, ww.w, a3);
                }
            }
        }
        float t = ((a0+a1) + (a2+a3)) + bias;
        out[(long long)b*784 + (qrt*7 + ohl)*28 + ow] = 1.f / (1.f + expf(-t));
    }
}

// ---------------- launch ----------------
extern "C" void kernel_launch(void* const* d_in, const int* in_sizes, int n_in,
                              void* d_out, int out_size, void* d_ws, size_t ws_size,
                              hipStream_t stream) {
    const int*   x    = (const int*)d_in[0];
    const float* encW = (const float*)d_in[1];
    const float* emb  = (const float*)d_in[2];
    const float* w1   = (const float*)d_in[3];
    const float* b1   = (const float*)d_in[4];
    const float* g1   = (const float*)d_in[5];
    const float* be1  = (const float*)d_in[6];
    const float* w2   = (const float*)d_in[7];
    const float* b2   = (const float*)d_in[8];
    const float* g2   = (const float*)d_in[9];
    const float* be2  = (const float*)d_in[10];
    const float* cw   = (const float*)d_in[11];
    const float* cb   = (const float*)d_in[12];
    float* out = (float*)d_out;

    char* ws = (char*)d_ws;
    float*          c1cls = (float*)(ws + WS_C1);
    float*          c2cls = (float*)(ws + WS_C2);
    double*         stats = (double*)(ws + WS_ST);
    float*          bnbuf = (float*)(ws + WS_BN);
    unsigned short* w1f   = (unsigned short*)(ws + WS_WF1);
    unsigned short* w2f   = (unsigned short*)(ws + WS_WF2);

    k_zero<<<1, 128, 0, stream>>>(stats);
    k_prep<<<128, 256, 0, stream>>>(w1, w2, w1f, w2f);
    k1_encode<<<784, 256, 0, stream>>>(x, encW, emb, out);
    k2_deconv1<<<2048, 256, 0, stream>>>(out + ZQ_OFF, w1f, b1, c1cls, stats);
    k_bnfin<<<1, 64, 0, stream>>>(stats, g1, be1, bnbuf, 0, 0, 32, 4096.0*196.0);
    k4_deconv2<<<4096, 256, 0, stream>>>(c1cls, w2f, b2, bnbuf, c2cls, stats);
    k_bnfin<<<1, 64, 0, stream>>>(stats, g2, be2, bnbuf, 64, 64, 16, 4096.0*784.0);
    k6_conv<<<16384, 256, 0, stream>>>(c2cls, cw, cb, bnbuf, out);
}

// Round 8
// 496.389 us; speedup vs baseline: 9.1626x; 1.4456x over previous
//
#include <hip/hip_runtime.h>
#include <hip/hip_bf16.h>
#include <math.h>

// ---------------- problem constants ----------------
#define BATCH   4096
#define CH      64          // latent channels
#define KCB     512         // codebook size

// d_out layout (floats): x_tilde [4096,1,28,28], z_e_x [4096,64,7,7], z_q_x [4096,64,7,7]
#define XT_N    (BATCH*784)
#define ZE_OFF  (XT_N)
#define ZQ_OFF  (XT_N + BATCH*3136)

// workspace layout (bytes)
// c1cls: [4096][4 cls][32 oc][49 px] fp32 = 102,760,448 B
// c2cls: [4096][4 cls][16 oc][196 px] fp32 = 205,520,896 B
#define WS_C1   0
#define WS_C2   102760448ULL
#define WS_ST   308281344ULL            // stats: double sum1[32] sq1[32] sum2[16] sq2[16]
#define WS_BN   308282112ULL            // bn params: float s1[32] h1[32] s2[16] h2[16]
#define WS_WF2  308282496ULL            // w2 MFMA frags bf16: 16 KiB
#define WS_EF   308298880ULL            // codebook hi/lo MFMA frags: 128 frags x 1 KiB = 128 KiB
#define WS_EE   308429952ULL            // ee[512] fp32 (fp64-accurate ||e||^2)
// w1 frags (64 KiB) live at the head of the C2 region: written by prep, read by k2,
// clobbered by k4's c2 writes (safe: stream order).
#define WS_WF1  WS_C2

typedef __attribute__((ext_vector_type(8))) __bf16 bf16x8;
typedef __attribute__((ext_vector_type(4))) float f32x4;
union B8 { uint4 u; bf16x8 v; };

__device__ inline unsigned short f2bf(float f) {   // RNE fp32->bf16
    unsigned int u = __float_as_uint(f);
    u = u + 0x7fffu + ((u >> 16) & 1u);
    return (unsigned short)(u >> 16);
}
__device__ inline float bf2f(unsigned short h) {
    return __uint_as_float(((unsigned int)h) << 16);
}

// ---------------- K0: zero the stats accumulators ----------------
__global__ void k_zero(double* __restrict__ stats) {
    int t = threadIdx.x;
    if (t < 96) stats[t] = 0.0;
}

// ---------------- prep: pack weights + codebook into per-lane MFMA fragments --------
// Shared slot rule (A and B identical): lane l, elem i -> k = kbase + 8*(l>>4) + i.
// A-side row = lane&15 (+16*mtile). Verified end-to-end by k2/k4 passing in r7.
// w1 frags: frag = cls*16 + tap*4 + khalf*2 + mt   (64 frags)
// w2 frags: frag = cls*4 + tap                     (16 frags)
// codebook frags (hi/lo split): frag = mt*4 + khalf*2 + hilo  (128 frags), cw = mt*16+(l&15)
__global__ void k_prep(const float* __restrict__ w1, const float* __restrict__ w2,
                       const float* __restrict__ emb,
                       unsigned short* __restrict__ w1f, unsigned short* __restrict__ w2f,
                       unsigned short* __restrict__ ef, float* __restrict__ eeW) {
    int t = threadIdx.x + blockIdx.x * 256;     // 0..65535
    {   // codebook hi/lo fragments
        int i = t & 7, lane = (t >> 3) & 63, frag = t >> 9;       // frag 0..127
        int mt = frag >> 2, khalf = (frag >> 1) & 1, hilo = frag & 1;
        int cw = mt * 16 + (lane & 15);
        int k  = khalf * 32 + ((lane >> 4) << 3) + i;
        float v = emb[(cw << 6) + k];
        unsigned short h = f2bf(v);
        ef[t] = hilo ? f2bf(v - bf2f(h)) : h;
    }
    if (t < 32768) {
        int i = t & 7, lane = (t >> 3) & 63, frag = t >> 9;
        int cls = frag >> 4, tap = (frag >> 2) & 3, khalf = (frag >> 1) & 1, mt = frag & 1;
        int ph = cls >> 1, pw = cls & 1, dh = tap >> 1, dw = tap & 1;
        int kh = (1 - ph) + 2 * dh, kw = (1 - pw) + 2 * dw;
        int oc = mt * 16 + (lane & 15);
        int ic = khalf * 32 + ((lane >> 4) << 3) + i;
        w1f[t] = f2bf(w1[((ic * 32 + oc) << 4) + kh * 4 + kw]);
    }
    if (t < 8192) {
        int i = t & 7, lane = (t >> 3) & 63, frag = t >> 9;   // frag < 16
        int cls = frag >> 2, tap = frag & 3;
        int ph = cls >> 1, pw = cls & 1, dh = tap >> 1, dw = tap & 1;
        int kh = (1 - ph) + 2 * dh, kw = (1 - pw) + 2 * dw;
        int oc = lane & 15;
        int ic = ((lane >> 4) << 3) + i;
        w2f[t] = f2bf(w2[((ic * 16 + oc) << 4) + kh * 4 + kw]);
    }
    if (t < KCB) {
        double s = 0.0;
        const float* e = emb + (t << 6);
        for (int c = 0; c < CH; ++c) s += (double)e[c] * (double)e[c];
        eeW[t] = (float)s;
    }
}

// ---------------- K1: gather + VQ argmin via split-bf16 MFMA + z_e_x/z_q_x ----------
// 128 positions/block (grid 1568). A=codebook (M=16 cw/tile, 32 tiles), B=z (N=16 pos/tile),
// K=64. dot = eh*zh + eh*zl + el*zh (error ~1e-8). score = ee - 2*dot (zz drops out of
// argmin). Top-2 + fp64 refine kept identical in spirit to the passing fp32 version.
__global__ __launch_bounds__(256) void k1_encode(
    const int* __restrict__ xidx, const float* __restrict__ encW,
    const float* __restrict__ emb, const unsigned short* __restrict__ ef,
    const float* __restrict__ eeW, float* __restrict__ out)
{
    __shared__ __align__(16) unsigned short zh_s[128*72];  // 144B rows -> 2-way alias (free)
    __shared__ __align__(16) unsigned short zl_s[128*72];
    __shared__ float ee_s[KCB];
    __shared__ float zzp[128][2];

    const int tid = threadIdx.x, wave = tid >> 6, lane = tid & 63;
    const int blk = blockIdx.x;

    for (int k = tid; k < KCB; k += 256) ee_s[k] = eeW[k];

    // stage z: hi/lo bf16 into LDS, copy z_e_x, partial zz
    {
        const int pos = tid & 127, h = tid >> 7;
        float zacc = 0.f;
        const int p  = blk*128 + pos;
        const int b  = p / 49;
        const int hw = p - b*49;
        const long long row = xidx[b];
        const float* rp = encW + row*3136LL + hw;
        float* zep = out + ZE_OFF + (long long)b*3136 + hw;
        #pragma unroll
        for (int j = 0; j < 32; ++j) {
            int c = h + 2*j;
            float v = rp[c*49];
            zep[c*49] = v;
            unsigned short hb = f2bf(v);
            float r = v - bf2f(hb);
            zh_s[pos*72 + c] = hb;
            zl_s[pos*72 + c] = f2bf(r);
            zacc = fmaf(v, v, zacc);
        }
        zzp[pos][h] = zacc;
    }
    __syncthreads();

    // B fragments for this wave's two N-tiles (pos = nt*16 + (lane&15))
    const int col = lane & 15, g = lane >> 4;
    B8 Bh[2][2], Bl[2][2];
    #pragma unroll
    for (int t2 = 0; t2 < 2; ++t2) {
        int pos = (wave*2 + t2)*16 + col;
        #pragma unroll
        for (int kh = 0; kh < 2; ++kh) {
            Bh[t2][kh].u = *(const uint4*)(zh_s + pos*72 + kh*32 + g*8);
            Bl[t2][kh].u = *(const uint4*)(zl_s + pos*72 + kh*32 + g*8);
        }
    }

    float d0[2] = {3.4e38f, 3.4e38f}, d1[2] = {3.4e38f, 3.4e38f};
    int   k0[2] = {0, 0},             k1i[2] = {1, 1};

    const uint4* ap = (const uint4*)ef + lane;
    uint4 A0 = ap[0*64], A1 = ap[1*64], A2 = ap[2*64], A3 = ap[3*64];  // hi0,lo0,hi1,lo1 of mt0

    for (int mt = 0; mt < 32; ++mt) {
        B8 Ah0, Al0, Ah1, Al1;
        Ah0.u = A0; Al0.u = A1; Ah1.u = A2; Al1.u = A3;
        if (mt < 31) {  // prefetch next tile's A-frags
            const uint4* np = ap + (mt+1)*256;
            A0 = np[0]; A1 = np[64]; A2 = np[128]; A3 = np[192];
        }
        const float4 eev = *(const float4*)&ee_s[mt*16 + (g << 2)];
        #pragma unroll
        for (int t2 = 0; t2 < 2; ++t2) {
            f32x4 acc = {eev.x*-0.5f, eev.y*-0.5f, eev.z*-0.5f, eev.w*-0.5f};
            acc = __builtin_amdgcn_mfma_f32_16x16x32_bf16(Ah0.v, Bh[t2][0].v, acc, 0,0,0);
            acc = __builtin_amdgcn_mfma_f32_16x16x32_bf16(Ah1.v, Bh[t2][1].v, acc, 0,0,0);
            acc = __builtin_amdgcn_mfma_f32_16x16x32_bf16(Ah0.v, Bl[t2][0].v, acc, 0,0,0);
            acc = __builtin_amdgcn_mfma_f32_16x16x32_bf16(Ah1.v, Bl[t2][1].v, acc, 0,0,0);
            acc = __builtin_amdgcn_mfma_f32_16x16x32_bf16(Al0.v, Bh[t2][0].v, acc, 0,0,0);
            acc = __builtin_amdgcn_mfma_f32_16x16x32_bf16(Al1.v, Bh[t2][1].v, acc, 0,0,0);
            #pragma unroll
            for (int rg = 0; rg < 4; ++rg) {
                float s = -2.f * acc[rg];           // = ee - 2*dot
                int  cw = mt*16 + (g << 2) + rg;
                if (s < d0[t2] || (s == d0[t2] && cw < k0[t2])) {
                    d1[t2] = d0[t2]; k1i[t2] = k0[t2]; d0[t2] = s; k0[t2] = cw;
                } else if (s < d1[t2] || (s == d1[t2] && cw < k1i[t2])) {
                    d1[t2] = s; k1i[t2] = cw;
                }
            }
        }
    }

    // merge top-2 across the 4 lane-groups (xor 16, 32), per N-tile
    #pragma unroll
    for (int t2 = 0; t2 < 2; ++t2) {
        #pragma unroll
        for (int msk = 16; msk <= 32; msk <<= 1) {
            float e0 = __shfl_xor(d0[t2], msk), e1 = __shfl_xor(d1[t2], msk);
            int   j0 = __shfl_xor(k0[t2], msk), j1 = __shfl_xor(k1i[t2], msk);
            if (e0 < d0[t2] || (e0 == d0[t2] && j0 < k0[t2])) {
                if (d0[t2] < e1 || (d0[t2] == e1 && k0[t2] < j1)) { d1[t2] = d0[t2]; k1i[t2] = k0[t2]; }
                else                                              { d1[t2] = e1;     k1i[t2] = j1;     }
                d0[t2] = e0; k0[t2] = j0;
            } else {
                if (e0 < d1[t2] || (e0 == d1[t2] && j0 < k1i[t2])) { d1[t2] = e0; k1i[t2] = j0; }
            }
        }

        const int pos = (wave*2 + t2)*16 + col;
        const int p   = blk*128 + pos;
        const int b   = p / 49;
        const int hw  = p - b*49;
        const float zz = zzp[pos][0] + zzp[pos][1];
        int win = k0[t2];

        // fp64 refine of near-ties (exact; engages rarely)
        if (d1[t2] - d0[t2] < fmaxf(1e-6f, 1e-3f * fabsf(d0[t2] + zz))) {
            const float* zp = out + ZE_OFF + (long long)b*3136 + hw;
            const float* ea = emb + k0[t2]*CH;
            const float* eb = emb + k1i[t2]*CH;
            double D0 = 0.0, D1 = 0.0;
            for (int c = 0; c < CH; ++c) {
                double zv = (double)zp[c*49];
                double f0 = zv - (double)ea[c];
                double f1 = zv - (double)eb[c];
                D0 += f0*f0; D1 += f1*f1;
            }
            if (D1 < D0 || (D1 == D0 && k1i[t2] < k0[t2])) win = k1i[t2];
        }

        // z_q_x: 4 lane-groups split the 64 channels (win identical across groups)
        float* zqp = out + ZQ_OFF + (long long)b*3136 + hw;
        const float* e0p = emb + win*CH + g*16;
        #pragma unroll
        for (int j = 0; j < 16; ++j) zqp[(g*16 + j)*49] = e0p[j];
    }
}

// ---------------- K2: deconv1 via MFMA (64->32, 7->14) + bias, BN1 stats ------------
// FROZEN (r7): 2 images/block, wave = parity class.
__global__ __launch_bounds__(256) void k2_deconv1(
    const float* __restrict__ zq, const unsigned short* __restrict__ w1f,
    const float* __restrict__ b1, float* __restrict__ c1cls,
    double* __restrict__ stats)
{
    __shared__ __align__(16) unsigned short x_s[2*81*72]; // [img][r<81][72 bf16] 23.3 KiB
    __shared__ float bs[32], bq[32];

    const int tid = threadIdx.x, wave = tid >> 6, lane = tid & 63;
    const int b0 = blockIdx.x << 1;

    for (int i = tid; i < 2*81*72/2; i += 256) ((unsigned int*)x_s)[i] = 0u;
    if (tid < 32) { bs[tid] = 0.f; bq[tid] = 0.f; }
    __syncthreads();

    for (int i = tid; i < 6272; i += 256) {
        int img = i >= 3136;
        int e = i - img*3136;
        int c = e / 49, hw = e - c*49;
        int ih = hw / 7, iw = hw - ih*7;
        float v = zq[(long long)(b0+img)*3136 + e];
        x_s[img*5832 + ((ih+1)*9 + (iw+1))*72 + c] = f2bf(v);
    }
    __syncthreads();

    const int cls = wave, ph = cls >> 1, pw = cls & 1;
    bf16x8 wfr[4][2][2];   // [tap][khalf][mtile]
    {
        const uint4* wp = (const uint4*)w1f + (cls*16)*64 + lane;
        #pragma unroll
        for (int tap = 0; tap < 4; ++tap)
            #pragma unroll
            for (int kh2 = 0; kh2 < 2; ++kh2)
                #pragma unroll
                for (int mt = 0; mt < 2; ++mt) {
                    B8 t; t.u = wp[(tap*4 + kh2*2 + mt)*64];
                    wfr[tap][kh2][mt] = t.v;
                }
    }
    float biasv[2][4];
    #pragma unroll
    for (int mt = 0; mt < 2; ++mt)
        #pragma unroll
        for (int rg = 0; rg < 4; ++rg)
            biasv[mt][rg] = b1[mt*16 + ((lane >> 4) << 2) + rg];

    float ts[2][4] = {{0.f}}, tq[2][4] = {{0.f}};
    const int gb = (lane >> 4) << 4;    // 16B granule for this lane's k-group

    for (int nt = 0; nt < 7; ++nt) {    // 7 N-tiles cover 98 px (2 img x 49)
        int m = nt*16 + (lane & 15);
        bool valid = m < 98;
        int mm = valid ? m : 0;
        int img = mm >= 49;
        int px = mm - img*49;
        int a = px / 7, bb = px - a*7;
        f32x4 acc0 = {0.f,0.f,0.f,0.f}, acc1 = {0.f,0.f,0.f,0.f};
        #pragma unroll
        for (int dh = 0; dh < 2; ++dh)
            #pragma unroll
            for (int dw = 0; dw < 2; ++dw) {
                int tap = dh*2 + dw;
                int r = (a + ph - dh + 1)*9 + (bb + pw - dw + 1);
                const char* p = (const char*)x_s + img*11664 + r*144 + gb;
                B8 x0; x0.u = *(const uint4*)p;          // ic 0..31 slice
                B8 x1; x1.u = *(const uint4*)(p + 64);   // ic 32..63 slice
                acc0 = __builtin_amdgcn_mfma_f32_16x16x32_bf16(wfr[tap][0][0], x0.v, acc0, 0,0,0);
                acc1 = __builtin_amdgcn_mfma_f32_16x16x32_bf16(wfr[tap][0][1], x0.v, acc1, 0,0,0);
                acc0 = __builtin_amdgcn_mfma_f32_16x16x32_bf16(wfr[tap][1][0], x1.v, acc0, 0,0,0);
                acc1 = __builtin_amdgcn_mfma_f32_16x16x32_bf16(wfr[tap][1][1], x1.v, acc1, 0,0,0);
            }
        if (valid) {
            float* base = c1cls + (long long)(b0+img)*6272 + cls*1568 + px;
            #pragma unroll
            for (int rg = 0; rg < 4; ++rg) {
                int oc = ((lane >> 4) << 2) + rg;
                float v0 = acc0[rg] + biasv[0][rg];
                float v1 = acc1[rg] + biasv[1][rg];
                base[oc*49]      = v0;
                base[(oc+16)*49] = v1;
                ts[0][rg] += v0; tq[0][rg] = fmaf(v0, v0, tq[0][rg]);
                ts[1][rg] += v1; tq[1][rg] = fmaf(v1, v1, tq[1][rg]);
            }
        }
    }

    #pragma unroll
    for (int mt = 0; mt < 2; ++mt)
        #pragma unroll
        for (int rg = 0; rg < 4; ++rg) {
            float s = ts[mt][rg], q = tq[mt][rg];
            #pragma unroll
            for (int msk = 1; msk < 16; msk <<= 1) {
                s += __shfl_xor(s, msk);
                q += __shfl_xor(q, msk);
            }
            if ((lane & 15) == 0) {
                int oc = mt*16 + ((lane >> 4) << 2) + rg;
                atomicAdd(&bs[oc], s);
                atomicAdd(&bq[oc], q);
            }
        }
    __syncthreads();
    if (tid < 32) {
        atomicAdd(&stats[tid],      (double)bs[tid]);
        atomicAdd(&stats[32 + tid], (double)bq[tid]);
    }
}

// ---------------- K3/K5: fold BN stats into scale/shift ----------------
__global__ void k_bnfin(const double* __restrict__ stats, const float* __restrict__ g,
                        const float* __restrict__ be, float* __restrict__ bn,
                        int soff, int boff, int nch, double n)
{
    int t = threadIdx.x;
    if (t < nch) {
        double mean = stats[soff + t] / n;
        double var  = stats[soff + nch + t] / n - mean*mean;
        double rstd = 1.0 / sqrt(var + 1e-5);
        double sc   = (double)g[t] * rstd;
        bn[boff + t]       = (float)sc;
        bn[boff + nch + t] = (float)((double)be[t] - mean*sc);
    }
}

// ---------------- K4: BN1+ReLU on read, deconv2 via MFMA (32->16, 14->28), BN2 stats -
// FROZEN (r7): 1 image/block, wave = parity class.
__global__ __launch_bounds__(256) void k4_deconv2(
    const float* __restrict__ c1cls, const unsigned short* __restrict__ w2f,
    const float* __restrict__ b2, const float* __restrict__ bn,
    float* __restrict__ c2cls, double* __restrict__ stats)
{
    __shared__ __align__(16) unsigned short x_s[256*40];  // [r<256][40 bf16] 20 KiB
    __shared__ float bnl[64];
    __shared__ float bs[16], bq[16];

    const int tid = threadIdx.x, wave = tid >> 6, lane = tid & 63;
    const int b = blockIdx.x;

    for (int i = tid; i < 256*40/2; i += 256) ((unsigned int*)x_s)[i] = 0u;
    if (tid < 64) bnl[tid] = bn[tid];
    if (tid < 16) { bs[tid] = 0.f; bq[tid] = 0.f; }
    __syncthreads();

    const float* cb = c1cls + (long long)b*6272;
    for (int i = tid; i < 6272; i += 256) {   // linear, fully coalesced
        int cl = i / 1568, e = i - cl*1568;
        int ic = e / 49, pxc = e - ic*49;
        int a = pxc / 7, bb = pxc - a*7;
        int ih = 2*a + (cl >> 1), iw = 2*bb + (cl & 1);
        float v = fmaxf(fmaf(cb[i], bnl[ic], bnl[32 + ic]), 0.f);
        x_s[((ih+1)*16 + (iw+1))*40 + ic] = f2bf(v);
    }
    __syncthreads();

    const int cls = wave, ph = cls >> 1, pw = cls & 1;
    bf16x8 wfr[4];
    {
        const uint4* wp = (const uint4*)w2f + (cls*4)*64 + lane;
        #pragma unroll
        for (int tap = 0; tap < 4; ++tap) { B8 t; t.u = wp[tap*64]; wfr[tap] = t.v; }
    }
    float biasv[4];
    #pragma unroll
    for (int rg = 0; rg < 4; ++rg) biasv[rg] = b2[((lane >> 4) << 2) + rg];

    float ts[4] = {0.f}, tq[4] = {0.f};
    float* c2b = c2cls + (long long)b*12544 + cls*3136;
    const int gb = (lane >> 4) << 4;

    for (int nt = 0; nt < 13; ++nt) {    // 13 N-tiles cover 196 px
        int m = nt*16 + (lane & 15);
        bool valid = m < 196;
        int px = valid ? m : 0;
        int a = px / 14, bb = px - a*14;
        f32x4 acc = {0.f,0.f,0.f,0.f};
        #pragma unroll
        for (int dh = 0; dh < 2; ++dh)
            #pragma unroll
            for (int dw = 0; dw < 2; ++dw) {
                int tap = dh*2 + dw;
                int r = (a + ph - dh + 1)*16 + (bb + pw - dw + 1);
                B8 x0; x0.u = *(const uint4*)((const char*)x_s + r*80 + gb);
                acc = __builtin_amdgcn_mfma_f32_16x16x32_bf16(wfr[tap], x0.v, acc, 0,0,0);
            }
        if (valid) {
            float* base = c2b + px;
            #pragma unroll
            for (int rg = 0; rg < 4; ++rg) {
                int oc = ((lane >> 4) << 2) + rg;
                float v = acc[rg] + biasv[rg];
                base[oc*196] = v;
                ts[rg] += v; tq[rg] = fmaf(v, v, tq[rg]);
            }
        }
    }

    #pragma unroll
    for (int rg = 0; rg < 4; ++rg) {
        float s = ts[rg], q = tq[rg];
        #pragma unroll
        for (int msk = 1; msk < 16; msk <<= 1) {
            s += __shfl_xor(s, msk);
            q += __shfl_xor(q, msk);
        }
        if ((lane & 15) == 0) {
            int oc = ((lane >> 4) << 2) + rg;
            atomicAdd(&bs[oc], s);
            atomicAdd(&bq[oc], q);
        }
    }
    __syncthreads();
    if (tid < 16) {
        atomicAdd(&stats[64 + tid], (double)bs[tid]);
        atomicAdd(&stats[80 + tid], (double)bq[tid]);
    }
}

// ---------------- K6: BN2+ReLU on read, 3x3 conv 16->1, sigmoid (fp32) --------------
// FROZEN (r7): quarter-image per block; reads class-major c2cls.
__global__ __launch_bounds__(256) void k6_conv(
    const float* __restrict__ c2cls, const float* __restrict__ cw,
    const float* __restrict__ cbias, const float* __restrict__ bn,
    float* __restrict__ out)
{
    __shared__ float x_s[9*31*16];      // [9 rows][31 col-slots][16 ch] 17.4 KiB
    __shared__ float w_s[144];          // [khw=9][ic=16]

    const int tid  = threadIdx.x;
    const int b    = blockIdx.x >> 2;
    const int qrt  = blockIdx.x & 3;    // output rows [qrt*7, qrt*7+7)
    const int r0   = qrt*7 - 1;         // first staged input row (may be -1)

    for (int i = tid; i < 9*31*16; i += 256) x_s[i] = 0.f;
    if (tid < 144) {
        int ic = tid / 9, khw = tid - ic*9;   // cw is [ic=16][kh][kw]
        w_s[khw*16 + ic] = cw[tid];
    }
    __syncthreads();

    const float* cr = c2cls + (long long)b*12544;
    for (int i = tid; i < 4032; i += 256) {           // 16 ch x 9 rows x 28 cols
        int c = i / 252, rem = i - c*252;
        int rr = rem / 28, iw = rem - rr*28;
        int ih = r0 + rr;
        if ((unsigned)ih < 28u) {
            int cl  = ((ih & 1) << 1) | (iw & 1);
            int px2 = (ih >> 1)*14 + (iw >> 1);
            float v = fmaxf(fmaf(cr[cl*3136 + c*196 + px2], bn[64 + c], bn[80 + c]), 0.f);
            x_s[(rr*31 + (iw+1))*16 + c] = v;
        }
    }
    __syncthreads();

    const float bias = cbias[0];
    const int px = tid;
    if (px < 196) {
        int ohl = px / 28, ow = px - ohl*28;
        float a0=0.f,a1=0.f,a2=0.f,a3=0.f;
        #pragma unroll
        for (int kh = 0; kh < 3; ++kh) {
            #pragma unroll
            for (int kw = 0; kw < 3; ++kw) {
                const float4* xv = (const float4*)&x_s[((ohl+kh)*31 + ow+kw)*16];
                const float4* wv = (const float4*)&w_s[((kh*3 + kw) << 4)];
                #pragma unroll
                for (int c4 = 0; c4 < 4; ++c4) {
                    float4 xx = xv[c4];
                    float4 ww = wv[c4];
                    a0 = fmaf(xx.x, ww.x, a0);
                    a1 = fmaf(xx.y, ww.y, a1);
                    a2 = fmaf(xx.z, ww.z, a2);
                    a3 = fmaf(xx.w, ww.w, a3);
                }
            }
        }
        float t = ((a0+a1) + (a2+a3)) + bias;
        out[(long long)b*784 + (qrt*7 + ohl)*28 + ow] = 1.f / (1.f + expf(-t));
    }
}

// ---------------- launch ----------------
extern "C" void kernel_launch(void* const* d_in, const int* in_sizes, int n_in,
                              void* d_out, int out_size, void* d_ws, size_t ws_size,
                              hipStream_t stream) {
    const int*   x    = (const int*)d_in[0];
    const float* encW = (const float*)d_in[1];
    const float* emb  = (const float*)d_in[2];
    const float* w1   = (const float*)d_in[3];
    const float* b1   = (const float*)d_in[4];
    const float* g1   = (const float*)d_in[5];
    const float* be1  = (const float*)d_in[6];
    const float* w2   = (const float*)d_in[7];
    const float* b2   = (const float*)d_in[8];
    const float* g2   = (const float*)d_in[9];
    const float* be2  = (const float*)d_in[10];
    const float* cw   = (const float*)d_in[11];
    const float* cb   = (const float*)d_in[12];
    float* out = (float*)d_out;

    char* ws = (char*)d_ws;
    float*          c1cls = (float*)(ws + WS_C1);
    float*          c2cls = (float*)(ws + WS_C2);
    double*         stats = (double*)(ws + WS_ST);
    float*          bnbuf = (float*)(ws + WS_BN);
    unsigned short* w1f   = (unsigned short*)(ws + WS_WF1);
    unsigned short* w2f   = (unsigned short*)(ws + WS_WF2);
    unsigned short* ef    = (unsigned short*)(ws + WS_EF);
    float*          eeW   = (float*)(ws + WS_EE);

    k_zero<<<1, 128, 0, stream>>>(stats);
    k_prep<<<256, 256, 0, stream>>>(w1, w2, emb, w1f, w2f, ef, eeW);
    k1_encode<<<1568, 256, 0, stream>>>(x, encW, emb, ef, eeW, out);
    k2_deconv1<<<2048, 256, 0, stream>>>(out + ZQ_OFF, w1f, b1, c1cls, stats);
    k_bnfin<<<1, 64, 0, stream>>>(stats, g1, be1, bnbuf, 0, 0, 32, 4096.0*196.0);
    k4_deconv2<<<4096, 256, 0, stream>>>(c1cls, w2f, b2, bnbuf, c2cls, stats);
    k_bnfin<<<1, 64, 0, stream>>>(stats, g2, be2, bnbuf, 64, 64, 16, 4096.0*784.0);
    k6_conv<<<16384, 256, 0, stream>>>(c2cls, cw, cb, bnbuf, out);
}

// Round 9
// 465.280 us; speedup vs baseline: 9.7752x; 1.0669x over previous
//
#include <hip/hip_runtime.h>
#include <hip/hip_bf16.h>
#include <math.h>

// ---------------- problem constants ----------------
#define BATCH   4096
#define CH      64          // latent channels
#define KCB     512         // codebook size

// d_out layout (floats): x_tilde [4096,1,28,28], z_e_x [4096,64,7,7], z_q_x [4096,64,7,7]
#define XT_N    (BATCH*784)
#define ZE_OFF  (XT_N)
#define ZQ_OFF  (XT_N + BATCH*3136)

// workspace layout (bytes) — c1/c2 now bf16
// c1cls: [4096][4 cls][32 oc][49 px] bf16 = 51,380,224 B
// c2cls: [4096][4 cls][16 oc][196 px] bf16 = 102,760,448 B
#define WS_C1   0
#define WS_C2   51380224ULL
#define WS_ST   154140672ULL            // stats: double sum1[32] sq1[32] sum2[16] sq2[16]
#define WS_WF2  154141824ULL            // w2 MFMA frags bf16: 16 KiB
#define WS_EF   154158208ULL            // codebook hi/lo MFMA frags: 128 KiB
#define WS_EE   154289280ULL            // ee[512] fp32 (fp64-accurate ||e||^2)
// w1 frags (64 KiB) live at the head of the C2 region: written by prep, read by k2,
// clobbered by k4's c2 writes (safe: stream order).
#define WS_WF1  WS_C2

typedef __attribute__((ext_vector_type(8))) __bf16 bf16x8;
typedef __attribute__((ext_vector_type(4))) float f32x4;
union B8 { uint4 u; bf16x8 v; };

__device__ inline unsigned short f2bf(float f) {   // RNE fp32->bf16
    unsigned int u = __float_as_uint(f);
    u = u + 0x7fffu + ((u >> 16) & 1u);
    return (unsigned short)(u >> 16);
}
__device__ inline float bf2f(unsigned short h) {
    return __uint_as_float(((unsigned int)h) << 16);
}

// ---------------- prep: pack weights + codebook into per-lane MFMA fragments --------
// Also zeroes the stats accumulators (block 0). Slot rule shared by A and B sides:
// lane l, elem i -> k = kbase + 8*(l>>4) + i. Verified end-to-end (r7/r8 pass).
__global__ void k_prep(const float* __restrict__ w1, const float* __restrict__ w2,
                       const float* __restrict__ emb,
                       unsigned short* __restrict__ w1f, unsigned short* __restrict__ w2f,
                       unsigned short* __restrict__ ef, float* __restrict__ eeW,
                       double* __restrict__ stats) {
    int t = threadIdx.x + blockIdx.x * 256;     // 0..65535
    if (t < 96) stats[t] = 0.0;
    {   // codebook hi/lo fragments
        int i = t & 7, lane = (t >> 3) & 63, frag = t >> 9;       // frag 0..127
        int mt = frag >> 2, khalf = (frag >> 1) & 1, hilo = frag & 1;
        int cw = mt * 16 + (lane & 15);
        int k  = khalf * 32 + ((lane >> 4) << 3) + i;
        float v = emb[(cw << 6) + k];
        unsigned short h = f2bf(v);
        ef[t] = hilo ? f2bf(v - bf2f(h)) : h;
    }
    if (t < 32768) {
        int i = t & 7, lane = (t >> 3) & 63, frag = t >> 9;
        int cls = frag >> 4, tap = (frag >> 2) & 3, khalf = (frag >> 1) & 1, mt = frag & 1;
        int ph = cls >> 1, pw = cls & 1, dh = tap >> 1, dw = tap & 1;
        int kh = (1 - ph) + 2 * dh, kw = (1 - pw) + 2 * dw;
        int oc = mt * 16 + (lane & 15);
        int ic = khalf * 32 + ((lane >> 4) << 3) + i;
        w1f[t] = f2bf(w1[((ic * 32 + oc) << 4) + kh * 4 + kw]);
    }
    if (t < 8192) {
        int i = t & 7, lane = (t >> 3) & 63, frag = t >> 9;   // frag < 16
        int cls = frag >> 2, tap = frag & 3;
        int ph = cls >> 1, pw = cls & 1, dh = tap >> 1, dw = tap & 1;
        int kh = (1 - ph) + 2 * dh, kw = (1 - pw) + 2 * dw;
        int oc = lane & 15;
        int ic = ((lane >> 4) << 3) + i;
        w2f[t] = f2bf(w2[((ic * 16 + oc) << 4) + kh * 4 + kw]);
    }
    if (t < KCB) {
        double s = 0.0;
        const float* e = emb + (t << 6);
        for (int c = 0; c < CH; ++c) s += (double)e[c] * (double)e[c];
        eeW[t] = (float)s;
    }
}

// ---------------- K1: gather + VQ argmin via split-bf16 MFMA + z_e_x/z_q_x ----------
// FROZEN (r8): 128 positions/block, dot = eh*zh + eh*zl + el*zh, top-2 + fp64 refine.
__global__ __launch_bounds__(256) void k1_encode(
    const int* __restrict__ xidx, const float* __restrict__ encW,
    const float* __restrict__ emb, const unsigned short* __restrict__ ef,
    const float* __restrict__ eeW, float* __restrict__ out)
{
    __shared__ __align__(16) unsigned short zh_s[128*72];  // 144B rows -> 2-way alias (free)
    __shared__ __align__(16) unsigned short zl_s[128*72];
    __shared__ float ee_s[KCB];
    __shared__ float zzp[128][2];

    const int tid = threadIdx.x, wave = tid >> 6, lane = tid & 63;
    const int blk = blockIdx.x;

    for (int k = tid; k < KCB; k += 256) ee_s[k] = eeW[k];

    {
        const int pos = tid & 127, h = tid >> 7;
        float zacc = 0.f;
        const int p  = blk*128 + pos;
        const int b  = p / 49;
        const int hw = p - b*49;
        const long long row = xidx[b];
        const float* rp = encW + row*3136LL + hw;
        float* zep = out + ZE_OFF + (long long)b*3136 + hw;
        #pragma unroll
        for (int j = 0; j < 32; ++j) {
            int c = h + 2*j;
            float v = rp[c*49];
            zep[c*49] = v;
            unsigned short hb = f2bf(v);
            float r = v - bf2f(hb);
            zh_s[pos*72 + c] = hb;
            zl_s[pos*72 + c] = f2bf(r);
            zacc = fmaf(v, v, zacc);
        }
        zzp[pos][h] = zacc;
    }
    __syncthreads();

    const int col = lane & 15, g = lane >> 4;
    B8 Bh[2][2], Bl[2][2];
    #pragma unroll
    for (int t2 = 0; t2 < 2; ++t2) {
        int pos = (wave*2 + t2)*16 + col;
        #pragma unroll
        for (int kh = 0; kh < 2; ++kh) {
            Bh[t2][kh].u = *(const uint4*)(zh_s + pos*72 + kh*32 + g*8);
            Bl[t2][kh].u = *(const uint4*)(zl_s + pos*72 + kh*32 + g*8);
        }
    }

    float d0[2] = {3.4e38f, 3.4e38f}, d1[2] = {3.4e38f, 3.4e38f};
    int   k0[2] = {0, 0},             k1i[2] = {1, 1};

    const uint4* ap = (const uint4*)ef + lane;
    uint4 A0 = ap[0*64], A1 = ap[1*64], A2 = ap[2*64], A3 = ap[3*64];

    for (int mt = 0; mt < 32; ++mt) {
        B8 Ah0, Al0, Ah1, Al1;
        Ah0.u = A0; Al0.u = A1; Ah1.u = A2; Al1.u = A3;
        if (mt < 31) {
            const uint4* np = ap + (mt+1)*256;
            A0 = np[0]; A1 = np[64]; A2 = np[128]; A3 = np[192];
        }
        const float4 eev = *(const float4*)&ee_s[mt*16 + (g << 2)];
        #pragma unroll
        for (int t2 = 0; t2 < 2; ++t2) {
            f32x4 acc = {eev.x*-0.5f, eev.y*-0.5f, eev.z*-0.5f, eev.w*-0.5f};
            acc = __builtin_amdgcn_mfma_f32_16x16x32_bf16(Ah0.v, Bh[t2][0].v, acc, 0,0,0);
            acc = __builtin_amdgcn_mfma_f32_16x16x32_bf16(Ah1.v, Bh[t2][1].v, acc, 0,0,0);
            acc = __builtin_amdgcn_mfma_f32_16x16x32_bf16(Ah0.v, Bl[t2][0].v, acc, 0,0,0);
            acc = __builtin_amdgcn_mfma_f32_16x16x32_bf16(Ah1.v, Bl[t2][1].v, acc, 0,0,0);
            acc = __builtin_amdgcn_mfma_f32_16x16x32_bf16(Al0.v, Bh[t2][0].v, acc, 0,0,0);
            acc = __builtin_amdgcn_mfma_f32_16x16x32_bf16(Al1.v, Bh[t2][1].v, acc, 0,0,0);
            #pragma unroll
            for (int rg = 0; rg < 4; ++rg) {
                float s = -2.f * acc[rg];
                int  cw = mt*16 + (g << 2) + rg;
                if (s < d0[t2] || (s == d0[t2] && cw < k0[t2])) {
                    d1[t2] = d0[t2]; k1i[t2] = k0[t2]; d0[t2] = s; k0[t2] = cw;
                } else if (s < d1[t2] || (s == d1[t2] && cw < k1i[t2])) {
                    d1[t2] = s; k1i[t2] = cw;
                }
            }
        }
    }

    #pragma unroll
    for (int t2 = 0; t2 < 2; ++t2) {
        #pragma unroll
        for (int msk = 16; msk <= 32; msk <<= 1) {
            float e0 = __shfl_xor(d0[t2], msk), e1 = __shfl_xor(d1[t2], msk);
            int   j0 = __shfl_xor(k0[t2], msk), j1 = __shfl_xor(k1i[t2], msk);
            if (e0 < d0[t2] || (e0 == d0[t2] && j0 < k0[t2])) {
                if (d0[t2] < e1 || (d0[t2] == e1 && k0[t2] < j1)) { d1[t2] = d0[t2]; k1i[t2] = k0[t2]; }
                else                                              { d1[t2] = e1;     k1i[t2] = j1;     }
                d0[t2] = e0; k0[t2] = j0;
            } else {
                if (e0 < d1[t2] || (e0 == d1[t2] && j0 < k1i[t2])) { d1[t2] = e0; k1i[t2] = j0; }
            }
        }

        const int pos = (wave*2 + t2)*16 + col;
        const int p   = blk*128 + pos;
        const int b   = p / 49;
        const int hw  = p - b*49;
        const float zz = zzp[pos][0] + zzp[pos][1];
        int win = k0[t2];

        if (d1[t2] - d0[t2] < fmaxf(1e-6f, 1e-3f * fabsf(d0[t2] + zz))) {
            const float* zp = out + ZE_OFF + (long long)b*3136 + hw;
            const float* ea = emb + k0[t2]*CH;
            const float* eb = emb + k1i[t2]*CH;
            double D0 = 0.0, D1 = 0.0;
            for (int c = 0; c < CH; ++c) {
                double zv = (double)zp[c*49];
                double f0 = zv - (double)ea[c];
                double f1 = zv - (double)eb[c];
                D0 += f0*f0; D1 += f1*f1;
            }
            if (D1 < D0 || (D1 == D0 && k1i[t2] < k0[t2])) win = k1i[t2];
        }

        float* zqp = out + ZQ_OFF + (long long)b*3136 + hw;
        const float* e0p = emb + win*CH + g*16;
        #pragma unroll
        for (int j = 0; j < 16; ++j) zqp[(g*16 + j)*49] = e0p[j];
    }
}

// ---------------- K2: deconv1 via MFMA (64->32, 7->14) + bias, BN1 stats ------------
// r7 structure; c1 stored bf16.
__global__ __launch_bounds__(256) void k2_deconv1(
    const float* __restrict__ zq, const unsigned short* __restrict__ w1f,
    const float* __restrict__ b1, unsigned short* __restrict__ c1cls,
    double* __restrict__ stats)
{
    __shared__ __align__(16) unsigned short x_s[2*81*72]; // [img][r<81][72 bf16] 23.3 KiB
    __shared__ float bs[32], bq[32];

    const int tid = threadIdx.x, wave = tid >> 6, lane = tid & 63;
    const int b0 = blockIdx.x << 1;

    for (int i = tid; i < 2*81*72/2; i += 256) ((unsigned int*)x_s)[i] = 0u;
    if (tid < 32) { bs[tid] = 0.f; bq[tid] = 0.f; }
    __syncthreads();

    for (int i = tid; i < 6272; i += 256) {
        int img = i >= 3136;
        int e = i - img*3136;
        int c = e / 49, hw = e - c*49;
        int ih = hw / 7, iw = hw - ih*7;
        float v = zq[(long long)(b0+img)*3136 + e];
        x_s[img*5832 + ((ih+1)*9 + (iw+1))*72 + c] = f2bf(v);
    }
    __syncthreads();

    const int cls = wave, ph = cls >> 1, pw = cls & 1;
    bf16x8 wfr[4][2][2];   // [tap][khalf][mtile]
    {
        const uint4* wp = (const uint4*)w1f + (cls*16)*64 + lane;
        #pragma unroll
        for (int tap = 0; tap < 4; ++tap)
            #pragma unroll
            for (int kh2 = 0; kh2 < 2; ++kh2)
                #pragma unroll
                for (int mt = 0; mt < 2; ++mt) {
                    B8 t; t.u = wp[(tap*4 + kh2*2 + mt)*64];
                    wfr[tap][kh2][mt] = t.v;
                }
    }
    float biasv[2][4];
    #pragma unroll
    for (int mt = 0; mt < 2; ++mt)
        #pragma unroll
        for (int rg = 0; rg < 4; ++rg)
            biasv[mt][rg] = b1[mt*16 + ((lane >> 4) << 2) + rg];

    float ts[2][4] = {{0.f}}, tq[2][4] = {{0.f}};
    const int gb = (lane >> 4) << 4;

    for (int nt = 0; nt < 7; ++nt) {
        int m = nt*16 + (lane & 15);
        bool valid = m < 98;
        int mm = valid ? m : 0;
        int img = mm >= 49;
        int px = mm - img*49;
        int a = px / 7, bb = px - a*7;
        f32x4 acc0 = {0.f,0.f,0.f,0.f}, acc1 = {0.f,0.f,0.f,0.f};
        #pragma unroll
        for (int dh = 0; dh < 2; ++dh)
            #pragma unroll
            for (int dw = 0; dw < 2; ++dw) {
                int tap = dh*2 + dw;
                int r = (a + ph - dh + 1)*9 + (bb + pw - dw + 1);
                const char* p = (const char*)x_s + img*11664 + r*144 + gb;
                B8 x0; x0.u = *(const uint4*)p;
                B8 x1; x1.u = *(const uint4*)(p + 64);
                acc0 = __builtin_amdgcn_mfma_f32_16x16x32_bf16(wfr[tap][0][0], x0.v, acc0, 0,0,0);
                acc1 = __builtin_amdgcn_mfma_f32_16x16x32_bf16(wfr[tap][0][1], x0.v, acc1, 0,0,0);
                acc0 = __builtin_amdgcn_mfma_f32_16x16x32_bf16(wfr[tap][1][0], x1.v, acc0, 0,0,0);
                acc1 = __builtin_amdgcn_mfma_f32_16x16x32_bf16(wfr[tap][1][1], x1.v, acc1, 0,0,0);
            }
        if (valid) {
            unsigned short* base = c1cls + (long long)(b0+img)*6272 + cls*1568 + px;
            #pragma unroll
            for (int rg = 0; rg < 4; ++rg) {
                int oc = ((lane >> 4) << 2) + rg;
                float v0 = acc0[rg] + biasv[0][rg];
                float v1 = acc1[rg] + biasv[1][rg];
                base[oc*49]      = f2bf(v0);
                base[(oc+16)*49] = f2bf(v1);
                ts[0][rg] += v0; tq[0][rg] = fmaf(v0, v0, tq[0][rg]);
                ts[1][rg] += v1; tq[1][rg] = fmaf(v1, v1, tq[1][rg]);
            }
        }
    }

    #pragma unroll
    for (int mt = 0; mt < 2; ++mt)
        #pragma unroll
        for (int rg = 0; rg < 4; ++rg) {
            float s = ts[mt][rg], q = tq[mt][rg];
            #pragma unroll
            for (int msk = 1; msk < 16; msk <<= 1) {
                s += __shfl_xor(s, msk);
                q += __shfl_xor(q, msk);
            }
            if ((lane & 15) == 0) {
                int oc = mt*16 + ((lane >> 4) << 2) + rg;
                atomicAdd(&bs[oc], s);
                atomicAdd(&bq[oc], q);
            }
        }
    __syncthreads();
    if (tid < 32) {
        atomicAdd(&stats[tid],      (double)bs[tid]);
        atomicAdd(&stats[32 + tid], (double)bq[tid]);
    }
}

// ---------------- K4: BN1 (from stats, folded) + ReLU, deconv2 via MFMA, BN2 stats ---
// r7 structure; c1 read bf16, c2 stored bf16; bnfin folded in (each block computes
// scale/shift redundantly from the fp64 stats).
__global__ __launch_bounds__(256) void k4_deconv2(
    const unsigned short* __restrict__ c1cls, const unsigned short* __restrict__ w2f,
    const float* __restrict__ b2, const float* __restrict__ g1,
    const float* __restrict__ be1, double* stats,
    unsigned short* __restrict__ c2cls)
{
    __shared__ __align__(16) unsigned short x_s[256*40];  // [r<256][40 bf16] 20 KiB
    __shared__ float bnl[64];
    __shared__ float bs[16], bq[16];

    const int tid = threadIdx.x, wave = tid >> 6, lane = tid & 63;
    const int b = blockIdx.x;

    for (int i = tid; i < 256*40/2; i += 256) ((unsigned int*)x_s)[i] = 0u;
    if (tid < 32) {
        const double n = 4096.0*196.0;
        double mean = stats[tid] / n;
        double var  = stats[32 + tid] / n - mean*mean;
        double rstd = 1.0 / sqrt(var + 1e-5);
        double sc   = (double)g1[tid] * rstd;
        bnl[tid]      = (float)sc;
        bnl[32 + tid] = (float)((double)be1[tid] - mean*sc);
    }
    if (tid < 16) { bs[tid] = 0.f; bq[tid] = 0.f; }
    __syncthreads();

    const unsigned short* cb = c1cls + (long long)b*6272;
    for (int i = tid; i < 6272; i += 256) {   // linear, fully coalesced
        int cl = i / 1568, e = i - cl*1568;
        int ic = e / 49, pxc = e - ic*49;
        int a = pxc / 7, bb = pxc - a*7;
        int ih = 2*a + (cl >> 1), iw = 2*bb + (cl & 1);
        float v = fmaxf(fmaf(bf2f(cb[i]), bnl[ic], bnl[32 + ic]), 0.f);
        x_s[((ih+1)*16 + (iw+1))*40 + ic] = f2bf(v);
    }
    __syncthreads();

    const int cls = wave, ph = cls >> 1, pw = cls & 1;
    bf16x8 wfr[4];
    {
        const uint4* wp = (const uint4*)w2f + (cls*4)*64 + lane;
        #pragma unroll
        for (int tap = 0; tap < 4; ++tap) { B8 t; t.u = wp[tap*64]; wfr[tap] = t.v; }
    }
    float biasv[4];
    #pragma unroll
    for (int rg = 0; rg < 4; ++rg) biasv[rg] = b2[((lane >> 4) << 2) + rg];

    float ts[4] = {0.f}, tq[4] = {0.f};
    unsigned short* c2b = c2cls + (long long)b*12544 + cls*3136;
    const int gb = (lane >> 4) << 4;

    for (int nt = 0; nt < 13; ++nt) {
        int m = nt*16 + (lane & 15);
        bool valid = m < 196;
        int px = valid ? m : 0;
        int a = px / 14, bb = px - a*14;
        f32x4 acc = {0.f,0.f,0.f,0.f};
        #pragma unroll
        for (int dh = 0; dh < 2; ++dh)
            #pragma unroll
            for (int dw = 0; dw < 2; ++dw) {
                int tap = dh*2 + dw;
                int r = (a + ph - dh + 1)*16 + (bb + pw - dw + 1);
                B8 x0; x0.u = *(const uint4*)((const char*)x_s + r*80 + gb);
                acc = __builtin_amdgcn_mfma_f32_16x16x32_bf16(wfr[tap], x0.v, acc, 0,0,0);
            }
        if (valid) {
            unsigned short* base = c2b + px;
            #pragma unroll
            for (int rg = 0; rg < 4; ++rg) {
                int oc = ((lane >> 4) << 2) + rg;
                float v = acc[rg] + biasv[rg];
                base[oc*196] = f2bf(v);
                ts[rg] += v; tq[rg] = fmaf(v, v, tq[rg]);
            }
        }
    }

    #pragma unroll
    for (int rg = 0; rg < 4; ++rg) {
        float s = ts[rg], q = tq[rg];
        #pragma unroll
        for (int msk = 1; msk < 16; msk <<= 1) {
            s += __shfl_xor(s, msk);
            q += __shfl_xor(q, msk);
        }
        if ((lane & 15) == 0) {
            int oc = ((lane >> 4) << 2) + rg;
            atomicAdd(&bs[oc], s);
            atomicAdd(&bq[oc], q);
        }
    }
    __syncthreads();
    if (tid < 16) {
        atomicAdd(&stats[64 + tid], (double)bs[tid]);
        atomicAdd(&stats[80 + tid], (double)bq[tid]);
    }
}

// ---------------- K6: BN2 (from stats, folded) + ReLU, 3x3 conv 16->1, sigmoid ------
// Quarter-image per block; c2 read bf16; bnfin folded in.
__global__ __launch_bounds__(256) void k6_conv(
    const unsigned short* __restrict__ c2cls, const float* __restrict__ cw,
    const float* __restrict__ cbias, const float* __restrict__ g2,
    const float* __restrict__ be2, const double* __restrict__ stats,
    float* __restrict__ out)
{
    __shared__ float x_s[9*31*16];      // [9 rows][31 col-slots][16 ch] 17.4 KiB
    __shared__ float w_s[144];          // [khw=9][ic=16]
    __shared__ float bn2[32];

    const int tid  = threadIdx.x;
    const int b    = blockIdx.x >> 2;
    const int qrt  = blockIdx.x & 3;    // output rows [qrt*7, qrt*7+7)
    const int r0   = qrt*7 - 1;         // first staged input row (may be -1)

    for (int i = tid; i < 9*31*16; i += 256) x_s[i] = 0.f;
    if (tid < 144) {
        int ic = tid / 9, khw = tid - ic*9;   // cw is [ic=16][kh][kw]
        w_s[khw*16 + ic] = cw[tid];
    }
    if (tid >= 192 && tid < 208) {
        int c = tid - 192;
        const double n = 4096.0*784.0;
        double mean = stats[64 + c] / n;
        double var  = stats[80 + c] / n - mean*mean;
        double rstd = 1.0 / sqrt(var + 1e-5);
        double sc   = (double)g2[c] * rstd;
        bn2[c]      = (float)sc;
        bn2[16 + c] = (float)((double)be2[c] - mean*sc);
    }
    __syncthreads();

    const unsigned short* cr = c2cls + (long long)b*12544;
    for (int i = tid; i < 4032; i += 256) {           // 16 ch x 9 rows x 28 cols
        int c = i / 252, rem = i - c*252;
        int rr = rem / 28, iw = rem - rr*28;
        int ih = r0 + rr;
        if ((unsigned)ih < 28u) {
            int cl  = ((ih & 1) << 1) | (iw & 1);
            int px2 = (ih >> 1)*14 + (iw >> 1);
            float v = fmaxf(fmaf(bf2f(cr[cl*3136 + c*196 + px2]), bn2[c], bn2[16 + c]), 0.f);
            x_s[(rr*31 + (iw+1))*16 + c] = v;
        }
    }
    __syncthreads();

    const float bias = cbias[0];
    const int px = tid;
    if (px < 196) {
        int ohl = px / 28, ow = px - ohl*28;
        float a0=0.f,a1=0.f,a2=0.f,a3=0.f;
        #pragma unroll
        for (int kh = 0; kh < 3; ++kh) {
            #pragma unroll
            for (int kw = 0; kw < 3; ++kw) {
                const float4* xv = (const float4*)&x_s[((ohl+kh)*31 + ow+kw)*16];
                const float4* wv = (const float4*)&w_s[((kh*3 + kw) << 4)];
                #pragma unroll
                for (int c4 = 0; c4 < 4; ++c4) {
                    float4 xx = xv[c4];
                    float4 ww = wv[c4];
                    a0 = fmaf(xx.x, ww.x, a0);
                    a1 = fmaf(xx.y, ww.y, a1);
                    a2 = fmaf(xx.z, ww.z, a2);
                    a3 = fmaf(xx.w, ww.w, a3);
                }
            }
        }
        float t = ((a0+a1) + (a2+a3)) + bias;
        out[(long long)b*784 + (qrt*7 + ohl)*28 + ow] = 1.f / (1.f + expf(-t));
    }
}

// ---------------- launch ----------------
extern "C" void kernel_launch(void* const* d_in, const int* in_sizes, int n_in,
                              void* d_out, int out_size, void* d_ws, size_t ws_size,
                              hipStream_t stream) {
    const int*   x    = (const int*)d_in[0];
    const float* encW = (const float*)d_in[1];
    const float* emb  = (const float*)d_in[2];
    const float* w1   = (const float*)d_in[3];
    const float* b1   = (const float*)d_in[4];
    const float* g1   = (const float*)d_in[5];
    const float* be1  = (const float*)d_in[6];
    const float* w2   = (const float*)d_in[7];
    const float* b2   = (const float*)d_in[8];
    const float* g2   = (const float*)d_in[9];
    const float* be2  = (const float*)d_in[10];
    const float* cw   = (const float*)d_in[11];
    const float* cb   = (const float*)d_in[12];
    float* out = (float*)d_out;

    char* ws = (char*)d_ws;
    unsigned short* c1cls = (unsigned short*)(ws + WS_C1);
    unsigned short* c2cls = (unsigned short*)(ws + WS_C2);
    double*         stats = (double*)(ws + WS_ST);
    unsigned short* w1f   = (unsigned short*)(ws + WS_WF1);
    unsigned short* w2f   = (unsigned short*)(ws + WS_WF2);
    unsigned short* ef    = (unsigned short*)(ws + WS_EF);
    float*          eeW   = (float*)(ws + WS_EE);

    k_prep<<<256, 256, 0, stream>>>(w1, w2, emb, w1f, w2f, ef, eeW, stats);
    k1_encode<<<1568, 256, 0, stream>>>(x, encW, emb, ef, eeW, out);
    k2_deconv1<<<2048, 256, 0, stream>>>(out + ZQ_OFF, w1f, b1, c1cls, stats);
    k4_deconv2<<<4096, 256, 0, stream>>>(c1cls, w2f, b2, g1, be1, stats, c2cls);
    k6_conv<<<16384, 256, 0, stream>>>(c2cls, cw, cb, g2, be2, stats, out);
}